// Round 7
// baseline (564.111 us; speedup 1.0000x reference)
//
#include <hip/hip_runtime.h>
#include <hip/hip_bf16.h>

#define T_DIM 4096
#define D_DIM 1024
#define DFF   2048
#define E_NUM 8

typedef short short8 __attribute__((ext_vector_type(8)));
typedef float f32x4  __attribute__((ext_vector_type(4)));

__device__ __forceinline__ unsigned short f2bf(float f) {
  union { float f; unsigned u; } v; v.f = f;
  unsigned r = v.u + 0x7FFFu + ((v.u >> 16) & 1u);   // round-to-nearest-even
  return (unsigned short)(r >> 16);
}

__device__ __forceinline__ void load_lds16(const unsigned short* g, unsigned short* l) {
  __builtin_amdgcn_global_load_lds((const __attribute__((address_space(1))) void*)g,
                                   (__attribute__((address_space(3))) void*)l, 16, 0, 0);
}

// ---------------- probe: one wave per token, all 8 experts (x read once).
__global__ void probe_kernel(const float* __restrict__ x, const float* __restrict__ Wp,
                             const float* __restrict__ bp, const float* __restrict__ tb,
                             const float* __restrict__ gm, const float* __restrict__ wdp,
                             float* __restrict__ scale) {
  int wave = threadIdx.x >> 6;
  int lane = threadIdx.x & 63;
  int t = blockIdx.x * 4 + wave;
  const float4* xr = (const float4*)(x + (size_t)t * D_DIM);
  float4 a[4];
#pragma unroll
  for (int k = 0; k < 4; k++) a[k] = xr[k * 64 + lane];
  float z = wdp[0] * 0.5f;                                  // w_depth * depth_ratio
  float tau = tb[0] + gm[0] * (z / (1.f + expf(-z)));       // tau_base + gamma*silu(z)
#pragma unroll
  for (int e = 0; e < E_NUM; e++) {
    const float4* wr = (const float4*)(Wp + (size_t)e * D_DIM);
    float acc = 0.f;
#pragma unroll
    for (int k = 0; k < 4; k++) {
      float4 b = wr[k * 64 + lane];
      acc += a[k].x * b.x + a[k].y * b.y + a[k].z * b.z + a[k].w * b.w;
    }
#pragma unroll
    for (int off = 32; off > 0; off >>= 1) acc += __shfl_down(acc, off);
    if (lane == 0) {
      float logit = acc + bp[e];
      scale[t * E_NUM + e] = (logit > tau) ? (1.f / (1.f + expf(-logit))) : 0.f;
    }
  }
}

// ---------------- per-expert token compaction + inverse map.
__global__ void compact_kernel(const float* __restrict__ scale, int* __restrict__ idxb,
                               float* __restrict__ scsb, int* __restrict__ cntb,
                               int* __restrict__ slotOfb) {
  int e = blockIdx.x;
  for (int t = threadIdx.x; t < T_DIM; t += 256) {
    float s = scale[t * E_NUM + e];
    if (s > 0.f) {                       // sigmoid(finite) > 0; inactive is exact 0
      int slot = atomicAdd(&cntb[e], 1);
      idxb[e * T_DIM + slot] = t;
      scsb[e * T_DIM + slot] = s;
      slotOfb[e * T_DIM + t] = slot;
    }
  }
}

// ---------------- fp32 -> bf16 converters
__global__ void cvt_kernel(const float* __restrict__ src, unsigned short* __restrict__ dst) {
  int i = blockIdx.x * 256 + threadIdx.x;   // one float4 per thread
  float4 v = ((const float4*)src)[i];
  ushort4 o;
  o.x = f2bf(v.x); o.y = f2bf(v.y); o.z = f2bf(v.z); o.w = f2bf(v.w);
  ((ushort4*)dst)[i] = o;
}

__global__ void cvt_w_kernel(const float* __restrict__ wu, const float* __restrict__ wg,
                             const float* __restrict__ wdn,
                             unsigned short* __restrict__ ou, unsigned short* __restrict__ og,
                             unsigned short* __restrict__ od) {
  int m = blockIdx.y;
  size_t i = (size_t)blockIdx.x * 256 + threadIdx.x;
  const float* s = (m == 0) ? wu : (m == 1) ? wg : wdn;
  unsigned short* d = (m == 0) ? ou : (m == 1) ? og : od;
  float4 v = ((const float4*)s)[i];
  ushort4 o;
  o.x = f2bf(v.x); o.y = f2bf(v.y); o.z = f2bf(v.z); o.w = f2bf(v.w);
  ((ushort4*)d)[i] = o;
}

__global__ void cvt3_kernel(const float* __restrict__ wu, const float* __restrict__ wg,
                            const float* __restrict__ wdn,
                            unsigned short* __restrict__ ou, unsigned short* __restrict__ og,
                            unsigned short* __restrict__ od) {
  int b = blockIdx.x;                 // 3 * 2048 blocks; 2048 per matrix
  int m = b >> 11;
  int i = (b & 2047) * 256 + threadIdx.x;
  const float* s = (m == 0) ? wu : (m == 1) ? wg : wdn;
  unsigned short* d = (m == 0) ? ou : (m == 1) ? og : od;
  float4 v = ((const float4*)s)[i];
  ushort4 o;
  o.x = f2bf(v.x); o.y = f2bf(v.y); o.z = f2bf(v.z); o.w = f2bf(v.w);
  ((ushort4*)d)[i] = o;
}

// ---------------- up+gate GEMM over compacted active tokens.
// Depth-2 pipeline, 3 LDS buffers (R5 depth-1 was latency-bound: stage wall ~= HBM
// latency). Per-iteration sync skeleton identical to the R5-verified pattern:
// counted vmcnt -> sched_barrier -> s_barrier -> compute -> lgkmcnt(0) -> s_barrier.
// Buffer safety: issue into buf (ks+2)%3 = buf of stage ks-1, drained at the
// previous iteration's closing barrier (B=3 >= K+1=3).
__global__ void __launch_bounds__(256, 2)
upgate_kernel(const unsigned short* __restrict__ A,
              const unsigned short* __restrict__ Bu_base,
              const unsigned short* __restrict__ Bg_base,
              size_t wstride, size_t hstride,
              const int* __restrict__ idxb, const float* __restrict__ scsb,
              const int* __restrict__ cntb, int e_base,
              unsigned short* __restrict__ H_base) {
  int x, y, z;
  if (gridDim.y == 1) {                   // fused: expert-affine XCD swizzle
    int wid = blockIdx.x;
    z = wid & 7;
    int i = wid >> 3;
    x = i & 31;                           // fastest: weight-tile reuse in L2
    y = i >> 5;
  } else {                                // fallback per-expert launch
    x = blockIdx.x; y = blockIdx.y; z = blockIdx.z;
  }
  const int e = e_base + z;
  const int rowA0 = x * 128;
  if (rowA0 >= cntb[e]) return;                          // inactive slot block (uniform)
  __shared__ unsigned short smem[3 * 12288];             // 73728 B, 3-deep
  const unsigned short* Bu = Bu_base + (size_t)z * wstride;
  const unsigned short* Bg = Bg_base + (size_t)z * wstride;
  unsigned short* H = H_base + (size_t)z * hstride;
  const int tid = threadIdx.x;
  const int wave = tid >> 6, lane = tid & 63;
  const int quad = lane >> 4, l15 = lane & 15;
  const int wm = (wave >> 1) * 64, wn = (wave & 1) * 64;
  const int rowB0 = y * 128;

  f32x4 accU[4][4], accG[4][4];
#pragma unroll
  for (int i2 = 0; i2 < 4; i2++)
#pragma unroll
    for (int j = 0; j < 4; j++) {
      accU[i2][j] = (f32x4){0.f, 0.f, 0.f, 0.f};
      accG[i2][j] = (f32x4){0.f, 0.f, 0.f, 0.f};
    }

  const int j0 = tid, j1 = tid + 256;          // 512 x 16B chunks per 8KB tile
  const int ar0 = rowA0 + (j0 >> 2), ar1 = rowA0 + (j1 >> 2);
  const int br0 = rowB0 + (j0 >> 2), br1 = rowB0 + (j1 >> 2);
  const int c0 = (j0 & 3) * 8, c1 = (j1 & 3) * 8;
  const int ta0 = idxb[e * T_DIM + ar0];       // slot -> token (pads -> 0, scs=0)
  const int ta1 = idxb[e * T_DIM + ar1];

#define UG_STAGE(buf, kk) do {                                                 \
    unsigned short* _b = smem + (buf) * 12288;                                 \
    load_lds16(A  + (size_t)ta0 * D_DIM + (kk) + c0, _b + j0 * 8);             \
    load_lds16(A  + (size_t)ta1 * D_DIM + (kk) + c1, _b + j1 * 8);             \
    load_lds16(Bu + (size_t)br0 * D_DIM + (kk) + c0, _b + 4096 + j0 * 8);      \
    load_lds16(Bu + (size_t)br1 * D_DIM + (kk) + c1, _b + 4096 + j1 * 8);      \
    load_lds16(Bg + (size_t)br0 * D_DIM + (kk) + c0, _b + 8192 + j0 * 8);      \
    load_lds16(Bg + (size_t)br1 * D_DIM + (kk) + c1, _b + 8192 + j1 * 8);      \
  } while (0)

  UG_STAGE(0, 0);                              // prologue: stages 0,1 in flight
  UG_STAGE(1, 32);
  for (int ks = 0; ks < 32; ks++) {
    if (ks < 30) {
      UG_STAGE((ks + 2) % 3, (ks + 2) * 32);   // issue stage ks+2 (6 loads)
      asm volatile("s_waitcnt vmcnt(12)" ::: "memory");  // stage ks landed, 2 in flight
    } else if (ks == 30) {
      asm volatile("s_waitcnt vmcnt(6)" ::: "memory");
    } else {
      asm volatile("s_waitcnt vmcnt(0)" ::: "memory");
    }
    __builtin_amdgcn_sched_barrier(0);
    __builtin_amdgcn_s_barrier();              // all waves' stage-ks data visible
    __builtin_amdgcn_sched_barrier(0);

    unsigned short* sA = smem + (ks % 3) * 12288;
    unsigned short* sU = sA + 4096;
    unsigned short* sG = sA + 8192;
    short8 af[4], bu[4], bg[4];
#pragma unroll
    for (int mt = 0; mt < 4; mt++)
      af[mt] = *(const short8*)(sA + (wm + mt * 16 + l15) * 32 + quad * 8);
#pragma unroll
    for (int nt = 0; nt < 4; nt++) {
      bu[nt] = *(const short8*)(sU + (wn + nt * 16 + l15) * 32 + quad * 8);
      bg[nt] = *(const short8*)(sG + (wn + nt * 16 + l15) * 32 + quad * 8);
    }
#pragma unroll
    for (int mt = 0; mt < 4; mt++)
#pragma unroll
      for (int nt = 0; nt < 4; nt++) {
        accU[mt][nt] = __builtin_amdgcn_mfma_f32_16x16x32_bf16(af[mt], bu[nt], accU[mt][nt], 0, 0, 0);
        accG[mt][nt] = __builtin_amdgcn_mfma_f32_16x16x32_bf16(af[mt], bg[nt], accG[mt][nt], 0, 0, 0);
      }
    // drain LDS reads of this buffer before any wave can overwrite it
    asm volatile("s_waitcnt lgkmcnt(0)" ::: "memory");
    __builtin_amdgcn_sched_barrier(0);
    __builtin_amdgcn_s_barrier();
    __builtin_amdgcn_sched_barrier(0);
  }
#undef UG_STAGE

  // epilogue: h' = scs[e,slot] * up * silu(gate)  (C/D: col=lane&15, row=quad*4+reg)
#pragma unroll
  for (int mt = 0; mt < 4; mt++) {
#pragma unroll
    for (int r = 0; r < 4; r++) {
      int row = rowA0 + wm + mt * 16 + quad * 4 + r;
      float s = scsb[e * T_DIM + row];
#pragma unroll
      for (int nt = 0; nt < 4; nt++) {
        int col = rowB0 + wn + nt * 16 + l15;
        float u = accU[mt][nt][r];
        float g = accG[mt][nt][r];
        float h = s * u * (g / (1.f + __expf(-g)));
        H[(size_t)row * DFF + col] = f2bf(h);
      }
    }
  }
}

// ---------------- fused-path down: dense-output-stationary gather GEMM, NO atomics.
// Depth-3 pipeline, 4 LDS buffers, steady vmcnt(9) (3 stages x 3 loads in flight).
// Per-expert h-row pointers hoisted into a fully-unrolled static array (no mid-loop
// slotOf loads perturbing the vmcnt discipline). Tail peels vmcnt 9->6->3->0.
__global__ void __launch_bounds__(256, 2)
down_dense_kernel(const unsigned short* __restrict__ hb,    // [E][slot][DFF]
                  const unsigned short* __restrict__ wdb,   // [E][D][DFF]
                  const int* __restrict__ slotOfb,          // [E][T], -1 = inactive
                  const unsigned short* __restrict__ zrow,  // DFF zeros
                  float* __restrict__ out) {
  const size_t HSZ = (size_t)T_DIM * DFF;
  const size_t WSZ = (size_t)D_DIM * DFF;
  int wid = blockIdx.x;                 // 512
  int xcd = wid & 7;
  int i = wid >> 3;                     // 0..63
  int y = i & 7;                        // D tile (fastest)
  int xloc = i >> 3;                    // 0..7
  int xt = xcd * 8 + xloc;              // token tile 0..63
  const int rowT0 = xt * 64, rowB0 = y * 128;

  __shared__ unsigned short smem[4 * 6144];   // 49152 B, 4-deep

  const int tid = threadIdx.x;
  const int wave = tid >> 6, lane = tid & 63;
  const int quad = lane >> 4, l15 = lane & 15;
  const int wn = wave * 32;             // wave tile: 64 rows x 32 cols

  f32x4 acc[4][2];
#pragma unroll
  for (int m = 0; m < 4; m++)
#pragma unroll
    for (int n = 0; n < 2; n++) acc[m][n] = (f32x4){0.f, 0.f, 0.f, 0.f};

  const int cA  = (tid & 3) * 8;
  const int j0 = tid, j1 = tid + 256;            // B: 2 chunks/thread (128 rows)
  const int brB0 = j0 >> 2, brB1 = j1 >> 2;      // 0..63, 64..127
  const int cB = (tid & 3) * 8;
  const int tA = rowT0 + (tid >> 2);             // dense token of my A row

  // hoist all 8 expert row pointers (static indexing under full unroll)
  const unsigned short* rowp[E_NUM];
#pragma unroll
  for (int e = 0; e < E_NUM; e++) {
    int s = slotOfb[e * T_DIM + tA];
    rowp[e] = (s >= 0) ? hb + (size_t)e * HSZ + (size_t)s * DFF : zrow;
  }

#define DN_STAGE(buf, ap, bp_, kk) do {                                         \
    unsigned short* _b = smem + (buf) * 6144;                                   \
    load_lds16((ap) + (kk) + cA, _b + tid * 8);                                 \
    load_lds16((bp_) + (size_t)brB0 * DFF + (kk) + cB, _b + 2048 + j0 * 8);     \
    load_lds16((bp_) + (size_t)brB1 * DFF + (kk) + cB, _b + 2048 + j1 * 8);     \
  } while (0)

  {
    const unsigned short* ap0 = rowp[0];
    const unsigned short* bp0 = wdb + (size_t)rowB0 * DFF;
    DN_STAGE(0, ap0, bp0, 0);                    // prologue: stages 0,1,2 in flight
    DN_STAGE(1, ap0, bp0, 32);
    DN_STAGE(2, ap0, bp0, 64);
  }

#pragma unroll
  for (int e = 0; e < E_NUM; e++) {
    const unsigned short* ap  = rowp[e];
    const unsigned short* bp_ = wdb + (size_t)e * WSZ + (size_t)rowB0 * DFF;
    const unsigned short* apN = (e < 7) ? rowp[(e < 7) ? e + 1 : e] : rowp[e];
    const unsigned short* bpN = wdb + (size_t)((e < 7) ? e + 1 : e) * WSZ + (size_t)rowB0 * DFF;
    for (int ks = 0; ks < 64; ks++) {
      if (e < 7 || ks < 61) {
        if (ks < 61) DN_STAGE((ks + 3) & 3, ap,  bp_, (ks + 3) * 32);
        else         DN_STAGE((ks + 3) & 3, apN, bpN, (ks - 61) * 32);
        asm volatile("s_waitcnt vmcnt(9)" ::: "memory");   // stage (e,ks) landed
      } else if (ks == 61) {
        asm volatile("s_waitcnt vmcnt(6)" ::: "memory");
      } else if (ks == 62) {
        asm volatile("s_waitcnt vmcnt(3)" ::: "memory");
      } else {
        asm volatile("s_waitcnt vmcnt(0)" ::: "memory");
      }
      __builtin_amdgcn_sched_barrier(0);
      __builtin_amdgcn_s_barrier();
      __builtin_amdgcn_sched_barrier(0);

      unsigned short* sA = smem + (ks & 3) * 6144;
      unsigned short* sB = sA + 2048;
      short8 af[4], bf[2];
#pragma unroll
      for (int mt = 0; mt < 4; mt++)
        af[mt] = *(const short8*)(sA + (mt * 16 + l15) * 32 + quad * 8);
#pragma unroll
      for (int nt = 0; nt < 2; nt++)
        bf[nt] = *(const short8*)(sB + (wn + nt * 16 + l15) * 32 + quad * 8);
#pragma unroll
      for (int mt = 0; mt < 4; mt++)
#pragma unroll
        for (int nt = 0; nt < 2; nt++)
          acc[mt][nt] = __builtin_amdgcn_mfma_f32_16x16x32_bf16(af[mt], bf[nt], acc[mt][nt], 0, 0, 0);
      // drain LDS reads of this buffer before it can be overwritten
      asm volatile("s_waitcnt lgkmcnt(0)" ::: "memory");
      __builtin_amdgcn_sched_barrier(0);
      __builtin_amdgcn_s_barrier();
      __builtin_amdgcn_sched_barrier(0);
    }
  }
#undef DN_STAGE

  // single plain store (each (row,col) owned by exactly one thread)
#pragma unroll
  for (int mt = 0; mt < 4; mt++) {
#pragma unroll
    for (int r = 0; r < 4; r++) {
      int row = rowT0 + mt * 16 + quad * 4 + r;
#pragma unroll
      for (int nt = 0; nt < 2; nt++) {
        int col = rowB0 + wn + nt * 16 + l15;
        out[(size_t)row * D_DIM + col] = acc[mt][nt][r];
      }
    }
  }
}

// ---------------- fallback down (atomic scatter) — used only when ws small
__global__ void __launch_bounds__(256, 2)
down_kernel(const unsigned short* __restrict__ A_base,
            const unsigned short* __restrict__ B_base,
            size_t hstride, size_t wstride,
            const int* __restrict__ idxb, const int* __restrict__ cntb, int e_base,
            float* __restrict__ out) {
  const int e = e_base + blockIdx.z;
  const int rowA0 = blockIdx.x * 128;
  if (rowA0 >= cntb[e]) return;
  __shared__ unsigned short smem[2 * 128 * 32];
  unsigned short* sA = smem;
  unsigned short* sB = smem + 4096;
  const unsigned short* A = A_base + (size_t)blockIdx.z * hstride;
  const unsigned short* B = B_base + (size_t)blockIdx.z * wstride;
  const int tid = threadIdx.x;
  const int wave = tid >> 6, lane = tid & 63;
  const int quad = lane >> 4, l15 = lane & 15;
  const int wm = (wave >> 1) * 64, wn = (wave & 1) * 64;
  const int rowB0 = blockIdx.y * 128;

  f32x4 acc[4][4];
#pragma unroll
  for (int i = 0; i < 4; i++)
#pragma unroll
    for (int j = 0; j < 4; j++) acc[i][j] = (f32x4){0.f, 0.f, 0.f, 0.f};

  const int j0 = tid, j1 = tid + 256;
  const int ar0 = rowA0 + (j0 >> 2), ar1 = rowA0 + (j1 >> 2);
  const int br0 = rowB0 + (j0 >> 2), br1 = rowB0 + (j1 >> 2);
  const int c0 = (j0 & 3) * 8, c1 = (j1 & 3) * 8;

  for (int k0 = 0; k0 < DFF; k0 += 32) {
    __syncthreads();
    load_lds16(A + (size_t)ar0 * DFF + k0 + c0, sA + j0 * 8);
    load_lds16(A + (size_t)ar1 * DFF + k0 + c1, sA + j1 * 8);
    load_lds16(B + (size_t)br0 * DFF + k0 + c0, sB + j0 * 8);
    load_lds16(B + (size_t)br1 * DFF + k0 + c1, sB + j1 * 8);
    __syncthreads();

    short8 af[4], bf[4];
#pragma unroll
    for (int mt = 0; mt < 4; mt++)
      af[mt] = *(const short8*)(sA + (wm + mt * 16 + l15) * 32 + quad * 8);
#pragma unroll
    for (int nt = 0; nt < 4; nt++)
      bf[nt] = *(const short8*)(sB + (wn + nt * 16 + l15) * 32 + quad * 8);
#pragma unroll
    for (int mt = 0; mt < 4; mt++)
#pragma unroll
      for (int nt = 0; nt < 4; nt++)
        acc[mt][nt] = __builtin_amdgcn_mfma_f32_16x16x32_bf16(af[mt], bf[nt], acc[mt][nt], 0, 0, 0);
  }

#pragma unroll
  for (int mt = 0; mt < 4; mt++) {
#pragma unroll
    for (int r = 0; r < 4; r++) {
      int row = rowA0 + wm + mt * 16 + quad * 4 + r;
      int tok = idxb[e * T_DIM + row];
#pragma unroll
      for (int nt = 0; nt < 4; nt++) {
        int col = rowB0 + wn + nt * 16 + l15;
        atomicAdd(&out[(size_t)tok * D_DIM + col], acc[mt][nt][r]);
      }
    }
  }
}

extern "C" void kernel_launch(void* const* d_in, const int* in_sizes, int n_in,
                              void* d_out, int out_size, void* d_ws, size_t ws_size,
                              hipStream_t stream) {
  const float* x   = (const float*)d_in[0];
  const float* Wp  = (const float*)d_in[1];
  const float* bp  = (const float*)d_in[2];
  const float* Wu  = (const float*)d_in[3];
  const float* Wg  = (const float*)d_in[4];
  const float* Wd  = (const float*)d_in[5];
  const float* tb  = (const float*)d_in[6];
  const float* gm  = (const float*)d_in[7];
  const float* wdp = (const float*)d_in[8];
  float* out = (float*)d_out;

  const size_t WSZ = (size_t)DFF * D_DIM;          // elements per expert weight matrix
  const size_t HSZ = (size_t)T_DIM * DFF;          // elements per expert h

  char* ws = (char*)d_ws;
  float* scale         = (float*)ws;                            // 128 KB @ 0
  int*   idxb          = (int*)(ws + 131072);                   // 128 KB
  float* scsb          = (float*)(ws + 262144);                 // 128 KB
  int*   slotOfb       = (int*)(ws + 393216);                   // 128 KB
  int*   cntb          = (int*)(ws + 524288);                   // 4 KB
  unsigned short* zrow = (unsigned short*)(ws + 528384);        // 8 KB zeros
  unsigned short* xb   = (unsigned short*)(ws + 536576);        // 8 MB
  const size_t HEAD    = 536576;

  hipMemsetAsync(ws + 131072, 0, 262144, stream);       // idxb + scsb = 0
  hipMemsetAsync(ws + 393216, 0xFF, 131072, stream);    // slotOf = -1
  hipMemsetAsync(ws + 524288, 0, 12288, stream);        // cntb + zrow = 0
  probe_kernel<<<T_DIM / 4, 256, 0, stream>>>(x, Wp, bp, tb, gm, wdp, scale);
  compact_kernel<<<E_NUM, 256, 0, stream>>>(scale, idxb, scsb, cntb, slotOfb);
  cvt_kernel<<<T_DIM * D_DIM / 1024, 256, 0, stream>>>(x, xb);

  const size_t FULL_REQ = HEAD + 8388608 + 3 * (WSZ * 2) * E_NUM + HSZ * 2 * E_NUM; // ~243.8 MB
  if (ws_size >= FULL_REQ) {
    // -------- fused path
    unsigned short* wub = xb + (size_t)T_DIM * D_DIM;           // 32 MB
    unsigned short* wgb = wub + WSZ * E_NUM;                    // 32 MB
    unsigned short* wdb = wgb + WSZ * E_NUM;                    // 32 MB
    unsigned short* hb  = wdb + WSZ * E_NUM;                    // 128 MB

    dim3 gc(WSZ * E_NUM / 1024, 3);
    cvt_w_kernel<<<gc, 256, 0, stream>>>(Wu, Wg, Wd, wub, wgb, wdb);

    // expert-affine XCD-swizzled 1D grids
    upgate_kernel<<<dim3(4096, 1, 1), 256, 0, stream>>>(xb, wub, wgb, WSZ, HSZ,
                                                        idxb, scsb, cntb, 0, hb);
    down_dense_kernel<<<dim3(512, 1, 1), 256, 0, stream>>>(hb, wdb, slotOfb, zrow, out);
  } else {
    // -------- fallback (~37 MB): per-expert loop, atomic down, out pre-zeroed
    hipMemsetAsync(out, 0, (size_t)T_DIM * D_DIM * sizeof(float), stream);
    unsigned short* wub = xb + (size_t)T_DIM * D_DIM;           // 4 MB
    unsigned short* wgb = wub + WSZ;                            // 4 MB
    unsigned short* wdb = wgb + WSZ;                            // 4 MB
    unsigned short* hb  = wdb + WSZ;                            // 16 MB

    for (int e = 0; e < E_NUM; e++) {
      cvt3_kernel<<<3 * (DFF * D_DIM / 1024), 256, 0, stream>>>(
          Wu + e * WSZ, Wg + e * WSZ, Wd + e * WSZ, wub, wgb, wdb);
      dim3 g1(T_DIM / 128, DFF / 128, 1);
      upgate_kernel<<<g1, 256, 0, stream>>>(xb, wub, wgb, 0, 0, idxb, scsb, cntb, e, hb);
      dim3 g2(T_DIM / 128, D_DIM / 128, 1);
      down_kernel<<<g2, 256, 0, stream>>>(hb, wdb, 0, 0, idxb, cntb, e, out);
    }
  }
}

// Round 9
// 472.877 us; speedup vs baseline: 1.1929x; 1.1929x over previous
//
#include <hip/hip_runtime.h>
#include <hip/hip_bf16.h>

#define T_DIM 4096
#define D_DIM 1024
#define DFF   2048
#define E_NUM 8

typedef short short8 __attribute__((ext_vector_type(8)));
typedef float f32x4  __attribute__((ext_vector_type(4)));

__device__ __forceinline__ unsigned short f2bf(float f) {
  union { float f; unsigned u; } v; v.f = f;
  unsigned r = v.u + 0x7FFFu + ((v.u >> 16) & 1u);   // round-to-nearest-even
  return (unsigned short)(r >> 16);
}

__device__ __forceinline__ float bf2f(unsigned short b) {
  union { unsigned u; float f; } v; v.u = ((unsigned)b) << 16; return v.f;
}

__device__ __forceinline__ void load_lds16(const unsigned short* g, unsigned short* l) {
  __builtin_amdgcn_global_load_lds((const __attribute__((address_space(1))) void*)g,
                                   (__attribute__((address_space(3))) void*)l, 16, 0, 0);
}

// ---------------- probe: one wave per token, all 8 experts (x read once).
__global__ void probe_kernel(const float* __restrict__ x, const float* __restrict__ Wp,
                             const float* __restrict__ bp, const float* __restrict__ tb,
                             const float* __restrict__ gm, const float* __restrict__ wdp,
                             float* __restrict__ scale) {
  int wave = threadIdx.x >> 6;
  int lane = threadIdx.x & 63;
  int t = blockIdx.x * 4 + wave;
  const float4* xr = (const float4*)(x + (size_t)t * D_DIM);
  float4 a[4];
#pragma unroll
  for (int k = 0; k < 4; k++) a[k] = xr[k * 64 + lane];
  float z = wdp[0] * 0.5f;                                  // w_depth * depth_ratio
  float tau = tb[0] + gm[0] * (z / (1.f + expf(-z)));       // tau_base + gamma*silu(z)
#pragma unroll
  for (int e = 0; e < E_NUM; e++) {
    const float4* wr = (const float4*)(Wp + (size_t)e * D_DIM);
    float acc = 0.f;
#pragma unroll
    for (int k = 0; k < 4; k++) {
      float4 b = wr[k * 64 + lane];
      acc += a[k].x * b.x + a[k].y * b.y + a[k].z * b.z + a[k].w * b.w;
    }
#pragma unroll
    for (int off = 32; off > 0; off >>= 1) acc += __shfl_down(acc, off);
    if (lane == 0) {
      float logit = acc + bp[e];
      scale[t * E_NUM + e] = (logit > tau) ? (1.f / (1.f + expf(-logit))) : 0.f;
    }
  }
}

// ---------------- per-expert token compaction + inverse map.
__global__ void compact_kernel(const float* __restrict__ scale, int* __restrict__ idxb,
                               float* __restrict__ scsb, int* __restrict__ cntb,
                               int* __restrict__ slotOfb) {
  int e = blockIdx.x;
  for (int t = threadIdx.x; t < T_DIM; t += 256) {
    float s = scale[t * E_NUM + e];
    if (s > 0.f) {                       // sigmoid(finite) > 0; inactive is exact 0
      int slot = atomicAdd(&cntb[e], 1);
      idxb[e * T_DIM + slot] = t;
      scsb[e * T_DIM + slot] = s;
      slotOfb[e * T_DIM + t] = slot;
    }
  }
}

// ---------------- fp32 -> bf16 converters
__global__ void cvt_kernel(const float* __restrict__ src, unsigned short* __restrict__ dst) {
  int i = blockIdx.x * 256 + threadIdx.x;   // one float4 per thread
  float4 v = ((const float4*)src)[i];
  ushort4 o;
  o.x = f2bf(v.x); o.y = f2bf(v.y); o.z = f2bf(v.z); o.w = f2bf(v.w);
  ((ushort4*)dst)[i] = o;
}

__global__ void cvt_w_kernel(const float* __restrict__ wu, const float* __restrict__ wg,
                             const float* __restrict__ wdn,
                             unsigned short* __restrict__ ou, unsigned short* __restrict__ og,
                             unsigned short* __restrict__ od) {
  int m = blockIdx.y;
  size_t i = (size_t)blockIdx.x * 256 + threadIdx.x;
  const float* s = (m == 0) ? wu : (m == 1) ? wg : wdn;
  unsigned short* d = (m == 0) ? ou : (m == 1) ? og : od;
  float4 v = ((const float4*)s)[i];
  ushort4 o;
  o.x = f2bf(v.x); o.y = f2bf(v.y); o.z = f2bf(v.z); o.w = f2bf(v.w);
  ((ushort4*)d)[i] = o;
}

__global__ void cvt3_kernel(const float* __restrict__ wu, const float* __restrict__ wg,
                            const float* __restrict__ wdn,
                            unsigned short* __restrict__ ou, unsigned short* __restrict__ og,
                            unsigned short* __restrict__ od) {
  int b = blockIdx.x;                 // 3 * 2048 blocks; 2048 per matrix
  int m = b >> 11;
  int i = (b & 2047) * 256 + threadIdx.x;
  const float* s = (m == 0) ? wu : (m == 1) ? wg : wdn;
  unsigned short* d = (m == 0) ? ou : (m == 1) ? og : od;
  float4 v = ((const float4*)s)[i];
  ushort4 o;
  o.x = f2bf(v.x); o.y = f2bf(v.y); o.z = f2bf(v.z); o.w = f2bf(v.w);
  ((ushort4*)d)[i] = o;
}

// ---------------- up+gate GEMM over compacted active tokens (R7-verified, unchanged).
__global__ void __launch_bounds__(256, 2)
upgate_kernel(const unsigned short* __restrict__ A,
              const unsigned short* __restrict__ Bu_base,
              const unsigned short* __restrict__ Bg_base,
              size_t wstride, size_t hstride,
              const int* __restrict__ idxb, const float* __restrict__ scsb,
              const int* __restrict__ cntb, int e_base,
              unsigned short* __restrict__ H_base) {
  int x, y, z;
  if (gridDim.y == 1) {                   // fused: expert-affine XCD swizzle
    int wid = blockIdx.x;
    z = wid & 7;
    int i = wid >> 3;
    x = i & 31;                           // fastest: weight-tile reuse in L2
    y = i >> 5;
  } else {                                // fallback per-expert launch
    x = blockIdx.x; y = blockIdx.y; z = blockIdx.z;
  }
  const int e = e_base + z;
  const int rowA0 = x * 128;
  if (rowA0 >= cntb[e]) return;                          // inactive slot block (uniform)
  __shared__ unsigned short smem[3 * 12288];             // 73728 B, 3-deep
  const unsigned short* Bu = Bu_base + (size_t)z * wstride;
  const unsigned short* Bg = Bg_base + (size_t)z * wstride;
  unsigned short* H = H_base + (size_t)z * hstride;
  const int tid = threadIdx.x;
  const int wave = tid >> 6, lane = tid & 63;
  const int quad = lane >> 4, l15 = lane & 15;
  const int wm = (wave >> 1) * 64, wn = (wave & 1) * 64;
  const int rowB0 = y * 128;

  f32x4 accU[4][4], accG[4][4];
#pragma unroll
  for (int i2 = 0; i2 < 4; i2++)
#pragma unroll
    for (int j = 0; j < 4; j++) {
      accU[i2][j] = (f32x4){0.f, 0.f, 0.f, 0.f};
      accG[i2][j] = (f32x4){0.f, 0.f, 0.f, 0.f};
    }

  const int j0 = tid, j1 = tid + 256;          // 512 x 16B chunks per 8KB tile
  const int ar0 = rowA0 + (j0 >> 2), ar1 = rowA0 + (j1 >> 2);
  const int br0 = rowB0 + (j0 >> 2), br1 = rowB0 + (j1 >> 2);
  const int c0 = (j0 & 3) * 8, c1 = (j1 & 3) * 8;
  const int ta0 = idxb[e * T_DIM + ar0];       // slot -> token (pads -> 0, scs=0)
  const int ta1 = idxb[e * T_DIM + ar1];

#define UG_STAGE(buf, kk) do {                                                 \
    unsigned short* _b = smem + (buf) * 12288;                                 \
    load_lds16(A  + (size_t)ta0 * D_DIM + (kk) + c0, _b + j0 * 8);             \
    load_lds16(A  + (size_t)ta1 * D_DIM + (kk) + c1, _b + j1 * 8);             \
    load_lds16(Bu + (size_t)br0 * D_DIM + (kk) + c0, _b + 4096 + j0 * 8);      \
    load_lds16(Bu + (size_t)br1 * D_DIM + (kk) + c1, _b + 4096 + j1 * 8);      \
    load_lds16(Bg + (size_t)br0 * D_DIM + (kk) + c0, _b + 8192 + j0 * 8);      \
    load_lds16(Bg + (size_t)br1 * D_DIM + (kk) + c1, _b + 8192 + j1 * 8);      \
  } while (0)

  UG_STAGE(0, 0);                              // prologue: stages 0,1 in flight
  UG_STAGE(1, 32);
  for (int ks = 0; ks < 32; ks++) {
    if (ks < 30) {
      UG_STAGE((ks + 2) % 3, (ks + 2) * 32);   // issue stage ks+2 (6 loads)
      asm volatile("s_waitcnt vmcnt(12)" ::: "memory");  // stage ks landed, 2 in flight
    } else if (ks == 30) {
      asm volatile("s_waitcnt vmcnt(6)" ::: "memory");
    } else {
      asm volatile("s_waitcnt vmcnt(0)" ::: "memory");
    }
    __builtin_amdgcn_sched_barrier(0);
    __builtin_amdgcn_s_barrier();              // all waves' stage-ks data visible
    __builtin_amdgcn_sched_barrier(0);

    unsigned short* sA = smem + (ks % 3) * 12288;
    unsigned short* sU = sA + 4096;
    unsigned short* sG = sA + 8192;
    short8 af[4], bu[4], bg[4];
#pragma unroll
    for (int mt = 0; mt < 4; mt++)
      af[mt] = *(const short8*)(sA + (wm + mt * 16 + l15) * 32 + quad * 8);
#pragma unroll
    for (int nt = 0; nt < 4; nt++) {
      bu[nt] = *(const short8*)(sU + (wn + nt * 16 + l15) * 32 + quad * 8);
      bg[nt] = *(const short8*)(sG + (wn + nt * 16 + l15) * 32 + quad * 8);
    }
#pragma unroll
    for (int mt = 0; mt < 4; mt++)
#pragma unroll
      for (int nt = 0; nt < 4; nt++) {
        accU[mt][nt] = __builtin_amdgcn_mfma_f32_16x16x32_bf16(af[mt], bu[nt], accU[mt][nt], 0, 0, 0);
        accG[mt][nt] = __builtin_amdgcn_mfma_f32_16x16x32_bf16(af[mt], bg[nt], accG[mt][nt], 0, 0, 0);
      }
    // drain LDS reads of this buffer before any wave can overwrite it
    asm volatile("s_waitcnt lgkmcnt(0)" ::: "memory");
    __builtin_amdgcn_sched_barrier(0);
    __builtin_amdgcn_s_barrier();
    __builtin_amdgcn_sched_barrier(0);
  }
#undef UG_STAGE

  // epilogue: h' = scs[e,slot] * up * silu(gate)  (C/D: col=lane&15, row=quad*4+reg)
#pragma unroll
  for (int mt = 0; mt < 4; mt++) {
#pragma unroll
    for (int r = 0; r < 4; r++) {
      int row = rowA0 + wm + mt * 16 + quad * 4 + r;
      float s = scsb[e * T_DIM + row];
#pragma unroll
      for (int nt = 0; nt < 4; nt++) {
        int col = rowB0 + wn + nt * 16 + l15;
        float u = accU[mt][nt][r];
        float g = accG[mt][nt][r];
        float h = s * u * (g / (1.f + __expf(-g)));
        H[(size_t)row * DFF + col] = f2bf(h);
      }
    }
  }
}

// ---------------- down pass 1: per-expert compacted GEMM de[e][slot][D] (bf16).
// A = h slot rows (CONTIGUOUS — no gather), B = wd. R8 BUGFIX: per-buffer is
// 8192 shorts (A-tile 128x32 = 4096 shorts + B-tile 4096 shorts at +4096); R8 had
// 4096/buffer with sB at +2048, aliasing A rows 64..127 with B rows 0..63.
__global__ void __launch_bounds__(256, 2)
down_slots_kernel(const unsigned short* __restrict__ hb,   // [E][slot][DFF]
                  const unsigned short* __restrict__ wdb,  // [E][D][DFF]
                  const int* __restrict__ cntb,
                  unsigned short* __restrict__ de) {       // [E][T][D] bf16
  int wid = blockIdx.x;                  // 2048
  const int e = wid & 7;                 // expert = XCD (round-robin affine)
  int i = wid >> 3;                      // 0..255
  const int x = i & 31;                  // slot tile, fastest (B-tile L2 reuse)
  const int y = i >> 5;                  // 0..7 D tile
  const int rowA0 = x * 128;
  if (rowA0 >= cntb[e]) return;          // uniform early-exit
  const size_t HSZ = (size_t)T_DIM * DFF;
  const size_t WSZ = (size_t)D_DIM * DFF;
  __shared__ unsigned short smem[3 * 8192];   // 49152 B, 3-deep (A 8KB + B 8KB each)
  const unsigned short* A = hb + (size_t)e * HSZ;
  const unsigned short* B = wdb + (size_t)e * WSZ;
  const int tid = threadIdx.x;
  const int wave = tid >> 6, lane = tid & 63;
  const int quad = lane >> 4, l15 = lane & 15;
  const int wm = (wave >> 1) * 64, wn = (wave & 1) * 64;
  const int rowB0 = y * 128;

  f32x4 acc[4][4];
#pragma unroll
  for (int i2 = 0; i2 < 4; i2++)
#pragma unroll
    for (int j = 0; j < 4; j++) acc[i2][j] = (f32x4){0.f, 0.f, 0.f, 0.f};

  const int j0 = tid, j1 = tid + 256;
  const int ar0 = rowA0 + (j0 >> 2), ar1 = rowA0 + (j1 >> 2);
  const int br0 = rowB0 + (j0 >> 2), br1 = rowB0 + (j1 >> 2);
  const int c0 = (j0 & 3) * 8, c1 = (j1 & 3) * 8;

#define DS_STAGE(buf, kk) do {                                                  \
    unsigned short* _b = smem + (buf) * 8192;                                   \
    load_lds16(A + (size_t)ar0 * DFF + (kk) + c0, _b + j0 * 8);                 \
    load_lds16(A + (size_t)ar1 * DFF + (kk) + c1, _b + j1 * 8);                 \
    load_lds16(B + (size_t)br0 * DFF + (kk) + c0, _b + 4096 + j0 * 8);          \
    load_lds16(B + (size_t)br1 * DFF + (kk) + c1, _b + 4096 + j1 * 8);          \
  } while (0)

  DS_STAGE(0, 0);                              // prologue: stages 0,1 in flight
  DS_STAGE(1, 32);
  for (int ks = 0; ks < 64; ks++) {
    if (ks < 62) {
      DS_STAGE((ks + 2) % 3, (ks + 2) * 32);   // issue stage ks+2 (4 loads)
      asm volatile("s_waitcnt vmcnt(8)" ::: "memory");   // stage ks landed
    } else if (ks == 62) {
      asm volatile("s_waitcnt vmcnt(4)" ::: "memory");
    } else {
      asm volatile("s_waitcnt vmcnt(0)" ::: "memory");
    }
    __builtin_amdgcn_sched_barrier(0);
    __builtin_amdgcn_s_barrier();
    __builtin_amdgcn_sched_barrier(0);

    unsigned short* sA = smem + (ks % 3) * 8192;
    unsigned short* sB = sA + 4096;
    short8 af[4], bf[4];
#pragma unroll
    for (int mt = 0; mt < 4; mt++)
      af[mt] = *(const short8*)(sA + (wm + mt * 16 + l15) * 32 + quad * 8);
#pragma unroll
    for (int nt = 0; nt < 4; nt++)
      bf[nt] = *(const short8*)(sB + (wn + nt * 16 + l15) * 32 + quad * 8);
#pragma unroll
    for (int mt = 0; mt < 4; mt++)
#pragma unroll
      for (int nt = 0; nt < 4; nt++)
        acc[mt][nt] = __builtin_amdgcn_mfma_f32_16x16x32_bf16(af[mt], bf[nt], acc[mt][nt], 0, 0, 0);
    // drain LDS reads of this buffer before any wave can overwrite it
    asm volatile("s_waitcnt lgkmcnt(0)" ::: "memory");
    __builtin_amdgcn_sched_barrier(0);
    __builtin_amdgcn_s_barrier();
    __builtin_amdgcn_sched_barrier(0);
  }
#undef DS_STAGE

  // plain store to compacted per-expert output (bf16)
#pragma unroll
  for (int mt = 0; mt < 4; mt++) {
#pragma unroll
    for (int r = 0; r < 4; r++) {
      int row = rowA0 + wm + mt * 16 + quad * 4 + r;    // slot
#pragma unroll
      for (int nt = 0; nt < 4; nt++) {
        int col = rowB0 + wn + nt * 16 + l15;
        de[((size_t)e * T_DIM + row) * D_DIM + col] = f2bf(acc[mt][nt][r]);
      }
    }
  }
}

// ---------------- down pass 2: gather-combine. out[t,:] = sum_e de[e][slotOf[e][t],:].
__global__ void combine_kernel(const unsigned short* __restrict__ de,
                               const int* __restrict__ slotOfb,
                               float* __restrict__ out) {
  int t = blockIdx.x;                    // 4096
  int d4 = threadIdx.x;                  // 256 chunks of 4 elems
  float4 acc = {0.f, 0.f, 0.f, 0.f};
#pragma unroll
  for (int e = 0; e < E_NUM; e++) {
    int s = slotOfb[e * T_DIM + t];      // block-uniform
    if (s >= 0) {
      ushort4 v = ((const ushort4*)(de + ((size_t)e * T_DIM + s) * D_DIM))[d4];
      acc.x += bf2f(v.x); acc.y += bf2f(v.y); acc.z += bf2f(v.z); acc.w += bf2f(v.w);
    }
  }
  ((float4*)(out + (size_t)t * D_DIM))[d4] = acc;
}

// ---------------- fallback down (atomic scatter) — used only when ws small
__global__ void __launch_bounds__(256, 2)
down_kernel(const unsigned short* __restrict__ A_base,
            const unsigned short* __restrict__ B_base,
            size_t hstride, size_t wstride,
            const int* __restrict__ idxb, const int* __restrict__ cntb, int e_base,
            float* __restrict__ out) {
  const int e = e_base + blockIdx.z;
  const int rowA0 = blockIdx.x * 128;
  if (rowA0 >= cntb[e]) return;
  __shared__ unsigned short smem[2 * 128 * 32];
  unsigned short* sA = smem;
  unsigned short* sB = smem + 4096;
  const unsigned short* A = A_base + (size_t)blockIdx.z * hstride;
  const unsigned short* B = B_base + (size_t)blockIdx.z * wstride;
  const int tid = threadIdx.x;
  const int wave = tid >> 6, lane = tid & 63;
  const int quad = lane >> 4, l15 = lane & 15;
  const int wm = (wave >> 1) * 64, wn = (wave & 1) * 64;
  const int rowB0 = blockIdx.y * 128;

  f32x4 acc[4][4];
#pragma unroll
  for (int i = 0; i < 4; i++)
#pragma unroll
    for (int j = 0; j < 4; j++) acc[i][j] = (f32x4){0.f, 0.f, 0.f, 0.f};

  const int j0 = tid, j1 = tid + 256;
  const int ar0 = rowA0 + (j0 >> 2), ar1 = rowA0 + (j1 >> 2);
  const int br0 = rowB0 + (j0 >> 2), br1 = rowB0 + (j1 >> 2);
  const int c0 = (j0 & 3) * 8, c1 = (j1 & 3) * 8;

  for (int k0 = 0; k0 < DFF; k0 += 32) {
    __syncthreads();
    load_lds16(A + (size_t)ar0 * DFF + k0 + c0, sA + j0 * 8);
    load_lds16(A + (size_t)ar1 * DFF + k0 + c1, sA + j1 * 8);
    load_lds16(B + (size_t)br0 * DFF + k0 + c0, sB + j0 * 8);
    load_lds16(B + (size_t)br1 * DFF + k0 + c1, sB + j1 * 8);
    __syncthreads();

    short8 af[4], bf[4];
#pragma unroll
    for (int mt = 0; mt < 4; mt++)
      af[mt] = *(const short8*)(sA + (wm + mt * 16 + l15) * 32 + quad * 8);
#pragma unroll
    for (int nt = 0; nt < 4; nt++)
      bf[nt] = *(const short8*)(sB + (wn + nt * 16 + l15) * 32 + quad * 8);
#pragma unroll
    for (int mt = 0; mt < 4; mt++)
#pragma unroll
      for (int nt = 0; nt < 4; nt++)
        acc[mt][nt] = __builtin_amdgcn_mfma_f32_16x16x32_bf16(af[mt], bf[nt], acc[mt][nt], 0, 0, 0);
  }

#pragma unroll
  for (int mt = 0; mt < 4; mt++) {
#pragma unroll
    for (int r = 0; r < 4; r++) {
      int row = rowA0 + wm + mt * 16 + quad * 4 + r;
      int tok = idxb[e * T_DIM + row];
#pragma unroll
      for (int nt = 0; nt < 4; nt++) {
        int col = rowB0 + wn + nt * 16 + l15;
        atomicAdd(&out[(size_t)tok * D_DIM + col], acc[mt][nt][r]);
      }
    }
  }
}

extern "C" void kernel_launch(void* const* d_in, const int* in_sizes, int n_in,
                              void* d_out, int out_size, void* d_ws, size_t ws_size,
                              hipStream_t stream) {
  const float* x   = (const float*)d_in[0];
  const float* Wp  = (const float*)d_in[1];
  const float* bp  = (const float*)d_in[2];
  const float* Wu  = (const float*)d_in[3];
  const float* Wg  = (const float*)d_in[4];
  const float* Wd  = (const float*)d_in[5];
  const float* tb  = (const float*)d_in[6];
  const float* gm  = (const float*)d_in[7];
  const float* wdp = (const float*)d_in[8];
  float* out = (float*)d_out;

  const size_t WSZ = (size_t)DFF * D_DIM;          // elements per expert weight matrix
  const size_t HSZ = (size_t)T_DIM * DFF;          // elements per expert h

  char* ws = (char*)d_ws;
  float* scale         = (float*)ws;                            // 128 KB @ 0
  int*   idxb          = (int*)(ws + 131072);                   // 128 KB
  float* scsb          = (float*)(ws + 262144);                 // 128 KB
  int*   slotOfb       = (int*)(ws + 393216);                   // 128 KB
  int*   cntb          = (int*)(ws + 524288);                   // 4 KB
  unsigned short* xb   = (unsigned short*)(ws + 536576);        // 8 MB
  const size_t HEAD    = 536576;

  hipMemsetAsync(ws + 131072, 0, 262144, stream);       // idxb + scsb = 0
  hipMemsetAsync(ws + 393216, 0xFF, 131072, stream);    // slotOf = -1
  hipMemsetAsync(ws + 524288, 0, 4096, stream);         // cntb = 0
  probe_kernel<<<T_DIM / 4, 256, 0, stream>>>(x, Wp, bp, tb, gm, wdp, scale);
  compact_kernel<<<E_NUM, 256, 0, stream>>>(scale, idxb, scsb, cntb, slotOfb);
  cvt_kernel<<<T_DIM * D_DIM / 1024, 256, 0, stream>>>(x, xb);

  const size_t FULL_REQ = HEAD + 8388608 + 3 * (WSZ * 2) * E_NUM + HSZ * 2 * E_NUM; // ~243.8 MB
  if (ws_size >= FULL_REQ) {
    // -------- fused path
    unsigned short* wub = xb + (size_t)T_DIM * D_DIM;           // 32 MB
    unsigned short* wgb = wub + WSZ * E_NUM;                    // 32 MB
    unsigned short* wdb = wgb + WSZ * E_NUM;                    // 32 MB
    unsigned short* hb  = wdb + WSZ * E_NUM;                    // 128 MB

    dim3 gc(WSZ * E_NUM / 1024, 3);
    cvt_w_kernel<<<gc, 256, 0, stream>>>(Wu, Wg, Wd, wub, wgb, wdb);

    // expert-affine XCD-swizzled 1D grids
    upgate_kernel<<<dim3(4096, 1, 1), 256, 0, stream>>>(xb, wub, wgb, WSZ, HSZ,
                                                        idxb, scsb, cntb, 0, hb);
    // de (bf16, [E][T][D] = 64 MB) reuses the wub+wgb region — dead after upgate
    unsigned short* de = wub;
    down_slots_kernel<<<dim3(2048, 1, 1), 256, 0, stream>>>(hb, wdb, cntb, de);
    combine_kernel<<<dim3(T_DIM, 1, 1), 256, 0, stream>>>(de, slotOfb, out);
  } else {
    // -------- fallback (~37 MB): per-expert loop, atomic down, out pre-zeroed
    hipMemsetAsync(out, 0, (size_t)T_DIM * D_DIM * sizeof(float), stream);
    unsigned short* wub = xb + (size_t)T_DIM * D_DIM;           // 4 MB
    unsigned short* wgb = wub + WSZ;                            // 4 MB
    unsigned short* wdb = wgb + WSZ;                            // 4 MB
    unsigned short* hb  = wdb + WSZ;                            // 16 MB

    for (int e = 0; e < E_NUM; e++) {
      cvt3_kernel<<<3 * (DFF * D_DIM / 1024), 256, 0, stream>>>(
          Wu + e * WSZ, Wg + e * WSZ, Wd + e * WSZ, wub, wgb, wdb);
      dim3 g1(T_DIM / 128, DFF / 128, 1);
      upgate_kernel<<<g1, 256, 0, stream>>>(xb, wub, wgb, 0, 0, idxb, scsb, cntb, e, hb);
      dim3 g2(T_DIM / 128, D_DIM / 128, 1);
      down_kernel<<<g2, 256, 0, stream>>>(hb, wdb, 0, 0, idxb, cntb, e, out);
    }
  }
}

// Round 10
// 471.641 us; speedup vs baseline: 1.1961x; 1.0026x over previous
//
#include <hip/hip_runtime.h>
#include <hip/hip_bf16.h>

#define T_DIM 4096
#define D_DIM 1024
#define DFF   2048
#define E_NUM 8

typedef short short8 __attribute__((ext_vector_type(8)));
typedef float f32x4  __attribute__((ext_vector_type(4)));

__device__ __forceinline__ unsigned short f2bf(float f) {
  union { float f; unsigned u; } v; v.f = f;
  unsigned r = v.u + 0x7FFFu + ((v.u >> 16) & 1u);   // round-to-nearest-even
  return (unsigned short)(r >> 16);
}

__device__ __forceinline__ float bf2f(unsigned short b) {
  union { unsigned u; float f; } v; v.u = ((unsigned)b) << 16; return v.f;
}

__device__ __forceinline__ void load_lds16(const unsigned short* g, unsigned short* l) {
  __builtin_amdgcn_global_load_lds((const __attribute__((address_space(1))) void*)g,
                                   (__attribute__((address_space(3))) void*)l, 16, 0, 0);
}

// ---------------- probe: one wave per token, all 8 experts (x read once).
__global__ void probe_kernel(const float* __restrict__ x, const float* __restrict__ Wp,
                             const float* __restrict__ bp, const float* __restrict__ tb,
                             const float* __restrict__ gm, const float* __restrict__ wdp,
                             float* __restrict__ scale) {
  int wave = threadIdx.x >> 6;
  int lane = threadIdx.x & 63;
  int t = blockIdx.x * 4 + wave;
  const float4* xr = (const float4*)(x + (size_t)t * D_DIM);
  float4 a[4];
#pragma unroll
  for (int k = 0; k < 4; k++) a[k] = xr[k * 64 + lane];
  float z = wdp[0] * 0.5f;                                  // w_depth * depth_ratio
  float tau = tb[0] + gm[0] * (z / (1.f + expf(-z)));       // tau_base + gamma*silu(z)
#pragma unroll
  for (int e = 0; e < E_NUM; e++) {
    const float4* wr = (const float4*)(Wp + (size_t)e * D_DIM);
    float acc = 0.f;
#pragma unroll
    for (int k = 0; k < 4; k++) {
      float4 b = wr[k * 64 + lane];
      acc += a[k].x * b.x + a[k].y * b.y + a[k].z * b.z + a[k].w * b.w;
    }
#pragma unroll
    for (int off = 32; off > 0; off >>= 1) acc += __shfl_down(acc, off);
    if (lane == 0) {
      float logit = acc + bp[e];
      scale[t * E_NUM + e] = (logit > tau) ? (1.f / (1.f + expf(-logit))) : 0.f;
    }
  }
}

// ---------------- per-expert token compaction + inverse map.
__global__ void compact_kernel(const float* __restrict__ scale, int* __restrict__ idxb,
                               float* __restrict__ scsb, int* __restrict__ cntb,
                               int* __restrict__ slotOfb) {
  int e = blockIdx.x;
  for (int t = threadIdx.x; t < T_DIM; t += 256) {
    float s = scale[t * E_NUM + e];
    if (s > 0.f) {                       // sigmoid(finite) > 0; inactive is exact 0
      int slot = atomicAdd(&cntb[e], 1);
      idxb[e * T_DIM + slot] = t;
      scsb[e * T_DIM + slot] = s;
      slotOfb[e * T_DIM + t] = slot;
    }
  }
}

// ---------------- fp32 -> bf16 converters
__global__ void cvt_kernel(const float* __restrict__ src, unsigned short* __restrict__ dst) {
  int i = blockIdx.x * 256 + threadIdx.x;   // one float4 per thread
  float4 v = ((const float4*)src)[i];
  ushort4 o;
  o.x = f2bf(v.x); o.y = f2bf(v.y); o.z = f2bf(v.z); o.w = f2bf(v.w);
  ((ushort4*)dst)[i] = o;
}

__global__ void cvt_w_kernel(const float* __restrict__ wu, const float* __restrict__ wg,
                             const float* __restrict__ wdn,
                             unsigned short* __restrict__ ou, unsigned short* __restrict__ og,
                             unsigned short* __restrict__ od) {
  int m = blockIdx.y;
  size_t i = (size_t)blockIdx.x * 256 + threadIdx.x;
  const float* s = (m == 0) ? wu : (m == 1) ? wg : wdn;
  unsigned short* d = (m == 0) ? ou : (m == 1) ? og : od;
  float4 v = ((const float4*)s)[i];
  ushort4 o;
  o.x = f2bf(v.x); o.y = f2bf(v.y); o.z = f2bf(v.z); o.w = f2bf(v.w);
  ((ushort4*)d)[i] = o;
}

__global__ void cvt3_kernel(const float* __restrict__ wu, const float* __restrict__ wg,
                            const float* __restrict__ wdn,
                            unsigned short* __restrict__ ou, unsigned short* __restrict__ og,
                            unsigned short* __restrict__ od) {
  int b = blockIdx.x;                 // 3 * 2048 blocks; 2048 per matrix
  int m = b >> 11;
  int i = (b & 2047) * 256 + threadIdx.x;
  const float* s = (m == 0) ? wu : (m == 1) ? wg : wdn;
  unsigned short* d = (m == 0) ? ou : (m == 1) ? og : od;
  float4 v = ((const float4*)s)[i];
  ushort4 o;
  o.x = f2bf(v.x); o.y = f2bf(v.y); o.z = f2bf(v.z); o.w = f2bf(v.w);
  ((ushort4*)d)[i] = o;
}

// ---------------- up+gate GEMM over compacted active tokens (R7/R9-verified, unchanged).
__global__ void __launch_bounds__(256, 2)
upgate_kernel(const unsigned short* __restrict__ A,
              const unsigned short* __restrict__ Bu_base,
              const unsigned short* __restrict__ Bg_base,
              size_t wstride, size_t hstride,
              const int* __restrict__ idxb, const float* __restrict__ scsb,
              const int* __restrict__ cntb, int e_base,
              unsigned short* __restrict__ H_base) {
  int x, y, z;
  if (gridDim.y == 1) {                   // fused: expert-affine XCD swizzle
    int wid = blockIdx.x;
    z = wid & 7;
    int i = wid >> 3;
    x = i & 31;                           // fastest: weight-tile reuse in L2
    y = i >> 5;
  } else {                                // fallback per-expert launch
    x = blockIdx.x; y = blockIdx.y; z = blockIdx.z;
  }
  const int e = e_base + z;
  const int rowA0 = x * 128;
  if (rowA0 >= cntb[e]) return;                          // inactive slot block (uniform)
  __shared__ unsigned short smem[3 * 12288];             // 73728 B, 3-deep
  const unsigned short* Bu = Bu_base + (size_t)z * wstride;
  const unsigned short* Bg = Bg_base + (size_t)z * wstride;
  unsigned short* H = H_base + (size_t)z * hstride;
  const int tid = threadIdx.x;
  const int wave = tid >> 6, lane = tid & 63;
  const int quad = lane >> 4, l15 = lane & 15;
  const int wm = (wave >> 1) * 64, wn = (wave & 1) * 64;
  const int rowB0 = y * 128;

  f32x4 accU[4][4], accG[4][4];
#pragma unroll
  for (int i2 = 0; i2 < 4; i2++)
#pragma unroll
    for (int j = 0; j < 4; j++) {
      accU[i2][j] = (f32x4){0.f, 0.f, 0.f, 0.f};
      accG[i2][j] = (f32x4){0.f, 0.f, 0.f, 0.f};
    }

  const int j0 = tid, j1 = tid + 256;          // 512 x 16B chunks per 8KB tile
  const int ar0 = rowA0 + (j0 >> 2), ar1 = rowA0 + (j1 >> 2);
  const int br0 = rowB0 + (j0 >> 2), br1 = rowB0 + (j1 >> 2);
  const int c0 = (j0 & 3) * 8, c1 = (j1 & 3) * 8;
  const int ta0 = idxb[e * T_DIM + ar0];       // slot -> token (pads -> 0, scs=0)
  const int ta1 = idxb[e * T_DIM + ar1];

#define UG_STAGE(buf, kk) do {                                                 \
    unsigned short* _b = smem + (buf) * 12288;                                 \
    load_lds16(A  + (size_t)ta0 * D_DIM + (kk) + c0, _b + j0 * 8);             \
    load_lds16(A  + (size_t)ta1 * D_DIM + (kk) + c1, _b + j1 * 8);             \
    load_lds16(Bu + (size_t)br0 * D_DIM + (kk) + c0, _b + 4096 + j0 * 8);      \
    load_lds16(Bu + (size_t)br1 * D_DIM + (kk) + c1, _b + 4096 + j1 * 8);      \
    load_lds16(Bg + (size_t)br0 * D_DIM + (kk) + c0, _b + 8192 + j0 * 8);      \
    load_lds16(Bg + (size_t)br1 * D_DIM + (kk) + c1, _b + 8192 + j1 * 8);      \
  } while (0)

  UG_STAGE(0, 0);                              // prologue: stages 0,1 in flight
  UG_STAGE(1, 32);
  for (int ks = 0; ks < 32; ks++) {
    if (ks < 30) {
      UG_STAGE((ks + 2) % 3, (ks + 2) * 32);   // issue stage ks+2 (6 loads)
      asm volatile("s_waitcnt vmcnt(12)" ::: "memory");  // stage ks landed, 2 in flight
    } else if (ks == 30) {
      asm volatile("s_waitcnt vmcnt(6)" ::: "memory");
    } else {
      asm volatile("s_waitcnt vmcnt(0)" ::: "memory");
    }
    __builtin_amdgcn_sched_barrier(0);
    __builtin_amdgcn_s_barrier();              // all waves' stage-ks data visible
    __builtin_amdgcn_sched_barrier(0);

    unsigned short* sA = smem + (ks % 3) * 12288;
    unsigned short* sU = sA + 4096;
    unsigned short* sG = sA + 8192;
    short8 af[4], bu[4], bg[4];
#pragma unroll
    for (int mt = 0; mt < 4; mt++)
      af[mt] = *(const short8*)(sA + (wm + mt * 16 + l15) * 32 + quad * 8);
#pragma unroll
    for (int nt = 0; nt < 4; nt++) {
      bu[nt] = *(const short8*)(sU + (wn + nt * 16 + l15) * 32 + quad * 8);
      bg[nt] = *(const short8*)(sG + (wn + nt * 16 + l15) * 32 + quad * 8);
    }
#pragma unroll
    for (int mt = 0; mt < 4; mt++)
#pragma unroll
      for (int nt = 0; nt < 4; nt++) {
        accU[mt][nt] = __builtin_amdgcn_mfma_f32_16x16x32_bf16(af[mt], bu[nt], accU[mt][nt], 0, 0, 0);
        accG[mt][nt] = __builtin_amdgcn_mfma_f32_16x16x32_bf16(af[mt], bg[nt], accG[mt][nt], 0, 0, 0);
      }
    // drain LDS reads of this buffer before any wave can overwrite it
    asm volatile("s_waitcnt lgkmcnt(0)" ::: "memory");
    __builtin_amdgcn_sched_barrier(0);
    __builtin_amdgcn_s_barrier();
    __builtin_amdgcn_sched_barrier(0);
  }
#undef UG_STAGE

  // epilogue: h' = scs[e,slot] * up * silu(gate)  (C/D: col=lane&15, row=quad*4+reg)
#pragma unroll
  for (int mt = 0; mt < 4; mt++) {
#pragma unroll
    for (int r = 0; r < 4; r++) {
      int row = rowA0 + wm + mt * 16 + quad * 4 + r;
      float s = scsb[e * T_DIM + row];
#pragma unroll
      for (int nt = 0; nt < 4; nt++) {
        int col = rowB0 + wn + nt * 16 + l15;
        float u = accU[mt][nt][r];
        float g = accG[mt][nt][r];
        float h = s * u * (g / (1.f + __expf(-g)));
        H[(size_t)row * DFF + col] = f2bf(h);
      }
    }
  }
}

// ---------------- down pass 1: per-expert compacted GEMM de[e][slot][D] (bf16).
// R10: SINGLE-barrier pipeline — 4 buffers, lookahead-2, one s_barrier per stage.
// Hazard calculus: buffer of stage g is re-targeted at body g+2; all waves' reads
// of it (issued body g-2... stage g-2's reads) were drained by the lgkmcnt(0)
// before the single barrier of body g-1, which every wave passes before any wave
// reaches body g's issue. The lgkmcnt(0) drains the PREVIOUS stage's ds_reads,
// which had a full MFMA phase to retire -> off the critical path.
// vmcnt: steady 8 (2 stages x 4 loads in flight), tail 4 -> 0.
__global__ void __launch_bounds__(256, 2)
down_slots_kernel(const unsigned short* __restrict__ hb,   // [E][slot][DFF]
                  const unsigned short* __restrict__ wdb,  // [E][D][DFF]
                  const int* __restrict__ cntb,
                  unsigned short* __restrict__ de) {       // [E][T][D] bf16
  int wid = blockIdx.x;                  // 2048
  const int e0 = wid & 7;                // expert = XCD (round-robin affine)
  int i = wid >> 3;                      // 0..255
  const int x = i & 31;                  // slot tile, fastest (B-tile L2 reuse)
  const int y = i >> 5;                  // 0..7 D tile
  const int rowA0 = x * 128;
  if (rowA0 >= cntb[e0]) return;         // uniform early-exit
  const size_t HSZ = (size_t)T_DIM * DFF;
  const size_t WSZ = (size_t)D_DIM * DFF;
  __shared__ unsigned short smem[4 * 8192];   // 65536 B, 4 buffers (A 8KB + B 8KB each)
  const int e = e0;
  const unsigned short* A = hb + (size_t)e * HSZ;
  const unsigned short* B = wdb + (size_t)e * WSZ;
  const int tid = threadIdx.x;
  const int wave = tid >> 6, lane = tid & 63;
  const int quad = lane >> 4, l15 = lane & 15;
  const int wm = (wave >> 1) * 64, wn = (wave & 1) * 64;
  const int rowB0 = y * 128;

  f32x4 acc[4][4];
#pragma unroll
  for (int i2 = 0; i2 < 4; i2++)
#pragma unroll
    for (int j = 0; j < 4; j++) acc[i2][j] = (f32x4){0.f, 0.f, 0.f, 0.f};

  const int j0 = tid, j1 = tid + 256;
  const int ar0 = rowA0 + (j0 >> 2), ar1 = rowA0 + (j1 >> 2);
  const int br0 = rowB0 + (j0 >> 2), br1 = rowB0 + (j1 >> 2);
  const int c0 = (j0 & 3) * 8, c1 = (j1 & 3) * 8;

#define DS_STAGE(buf, kk) do {                                                  \
    unsigned short* _b = smem + (buf) * 8192;                                   \
    load_lds16(A + (size_t)ar0 * DFF + (kk) + c0, _b + j0 * 8);                 \
    load_lds16(A + (size_t)ar1 * DFF + (kk) + c1, _b + j1 * 8);                 \
    load_lds16(B + (size_t)br0 * DFF + (kk) + c0, _b + 4096 + j0 * 8);          \
    load_lds16(B + (size_t)br1 * DFF + (kk) + c1, _b + 4096 + j1 * 8);          \
  } while (0)

  DS_STAGE(0, 0);                              // prologue: stages 0,1 in flight
  DS_STAGE(1, 32);
  for (int ks = 0; ks < 64; ks++) {
    if (ks < 62) {
      DS_STAGE((ks + 2) & 3, (ks + 2) * 32);   // issue stage ks+2 (4 loads)
      asm volatile("s_waitcnt vmcnt(8)" ::: "memory");   // stage ks landed
    } else if (ks == 62) {
      asm volatile("s_waitcnt vmcnt(4)" ::: "memory");
    } else {
      asm volatile("s_waitcnt vmcnt(0)" ::: "memory");
    }
    // drain PREVIOUS stage's ds_reads (had the whole MFMA phase to retire),
    // then the single barrier: stage-ks data visible AND buf (ks-2) freed.
    asm volatile("s_waitcnt lgkmcnt(0)" ::: "memory");
    __builtin_amdgcn_sched_barrier(0);
    __builtin_amdgcn_s_barrier();
    __builtin_amdgcn_sched_barrier(0);

    unsigned short* sA = smem + (ks & 3) * 8192;
    unsigned short* sB = sA + 4096;
    short8 af[4], bf[4];
#pragma unroll
    for (int mt = 0; mt < 4; mt++)
      af[mt] = *(const short8*)(sA + (wm + mt * 16 + l15) * 32 + quad * 8);
#pragma unroll
    for (int nt = 0; nt < 4; nt++)
      bf[nt] = *(const short8*)(sB + (wn + nt * 16 + l15) * 32 + quad * 8);
#pragma unroll
    for (int mt = 0; mt < 4; mt++)
#pragma unroll
      for (int nt = 0; nt < 4; nt++)
        acc[mt][nt] = __builtin_amdgcn_mfma_f32_16x16x32_bf16(af[mt], bf[nt], acc[mt][nt], 0, 0, 0);
    __builtin_amdgcn_sched_barrier(0);         // keep reads/MFMA inside this iteration
  }
#undef DS_STAGE

  // plain store to compacted per-expert output (bf16)
#pragma unroll
  for (int mt = 0; mt < 4; mt++) {
#pragma unroll
    for (int r = 0; r < 4; r++) {
      int row = rowA0 + wm + mt * 16 + quad * 4 + r;    // slot
#pragma unroll
      for (int nt = 0; nt < 4; nt++) {
        int col = rowB0 + wn + nt * 16 + l15;
        de[((size_t)e * T_DIM + row) * D_DIM + col] = f2bf(acc[mt][nt][r]);
      }
    }
  }
}

// ---------------- down pass 2: gather-combine. out[t,:] = sum_e de[e][slotOf[e][t],:].
__global__ void combine_kernel(const unsigned short* __restrict__ de,
                               const int* __restrict__ slotOfb,
                               float* __restrict__ out) {
  int t = blockIdx.x;                    // 4096
  int d4 = threadIdx.x;                  // 256 chunks of 4 elems
  float4 acc = {0.f, 0.f, 0.f, 0.f};
#pragma unroll
  for (int e = 0; e < E_NUM; e++) {
    int s = slotOfb[e * T_DIM + t];      // block-uniform
    if (s >= 0) {
      ushort4 v = ((const ushort4*)(de + ((size_t)e * T_DIM + s) * D_DIM))[d4];
      acc.x += bf2f(v.x); acc.y += bf2f(v.y); acc.z += bf2f(v.z); acc.w += bf2f(v.w);
    }
  }
  ((float4*)(out + (size_t)t * D_DIM))[d4] = acc;
}

// ---------------- fallback down (atomic scatter) — used only when ws small
__global__ void __launch_bounds__(256, 2)
down_kernel(const unsigned short* __restrict__ A_base,
            const unsigned short* __restrict__ B_base,
            size_t hstride, size_t wstride,
            const int* __restrict__ idxb, const int* __restrict__ cntb, int e_base,
            float* __restrict__ out) {
  const int e = e_base + blockIdx.z;
  const int rowA0 = blockIdx.x * 128;
  if (rowA0 >= cntb[e]) return;
  __shared__ unsigned short smem[2 * 128 * 32];
  unsigned short* sA = smem;
  unsigned short* sB = smem + 4096;
  const unsigned short* A = A_base + (size_t)blockIdx.z * hstride;
  const unsigned short* B = B_base + (size_t)blockIdx.z * wstride;
  const int tid = threadIdx.x;
  const int wave = tid >> 6, lane = tid & 63;
  const int quad = lane >> 4, l15 = lane & 15;
  const int wm = (wave >> 1) * 64, wn = (wave & 1) * 64;
  const int rowB0 = blockIdx.y * 128;

  f32x4 acc[4][4];
#pragma unroll
  for (int i = 0; i < 4; i++)
#pragma unroll
    for (int j = 0; j < 4; j++) acc[i][j] = (f32x4){0.f, 0.f, 0.f, 0.f};

  const int j0 = tid, j1 = tid + 256;
  const int ar0 = rowA0 + (j0 >> 2), ar1 = rowA0 + (j1 >> 2);
  const int br0 = rowB0 + (j0 >> 2), br1 = rowB0 + (j1 >> 2);
  const int c0 = (j0 & 3) * 8, c1 = (j1 & 3) * 8;

  for (int k0 = 0; k0 < DFF; k0 += 32) {
    __syncthreads();
    load_lds16(A + (size_t)ar0 * DFF + k0 + c0, sA + j0 * 8);
    load_lds16(A + (size_t)ar1 * DFF + k0 + c1, sA + j1 * 8);
    load_lds16(B + (size_t)br0 * DFF + k0 + c0, sB + j0 * 8);
    load_lds16(B + (size_t)br1 * DFF + k0 + c1, sB + j1 * 8);
    __syncthreads();

    short8 af[4], bf[4];
#pragma unroll
    for (int mt = 0; mt < 4; mt++)
      af[mt] = *(const short8*)(sA + (wm + mt * 16 + l15) * 32 + quad * 8);
#pragma unroll
    for (int nt = 0; nt < 4; nt++)
      bf[nt] = *(const short8*)(sB + (wn + nt * 16 + l15) * 32 + quad * 8);
#pragma unroll
    for (int mt = 0; mt < 4; mt++)
#pragma unroll
      for (int nt = 0; nt < 4; nt++)
        acc[mt][nt] = __builtin_amdgcn_mfma_f32_16x16x32_bf16(af[mt], bf[nt], acc[mt][nt], 0, 0, 0);
  }

#pragma unroll
  for (int mt = 0; mt < 4; mt++) {
#pragma unroll
    for (int r = 0; r < 4; r++) {
      int row = rowA0 + wm + mt * 16 + quad * 4 + r;
      int tok = idxb[e * T_DIM + row];
#pragma unroll
      for (int nt = 0; nt < 4; nt++) {
        int col = rowB0 + wn + nt * 16 + l15;
        atomicAdd(&out[(size_t)tok * D_DIM + col], acc[mt][nt][r]);
      }
    }
  }
}

extern "C" void kernel_launch(void* const* d_in, const int* in_sizes, int n_in,
                              void* d_out, int out_size, void* d_ws, size_t ws_size,
                              hipStream_t stream) {
  const float* x   = (const float*)d_in[0];
  const float* Wp  = (const float*)d_in[1];
  const float* bp  = (const float*)d_in[2];
  const float* Wu  = (const float*)d_in[3];
  const float* Wg  = (const float*)d_in[4];
  const float* Wd  = (const float*)d_in[5];
  const float* tb  = (const float*)d_in[6];
  const float* gm  = (const float*)d_in[7];
  const float* wdp = (const float*)d_in[8];
  float* out = (float*)d_out;

  const size_t WSZ = (size_t)DFF * D_DIM;          // elements per expert weight matrix
  const size_t HSZ = (size_t)T_DIM * DFF;          // elements per expert h

  char* ws = (char*)d_ws;
  float* scale         = (float*)ws;                            // 128 KB @ 0
  int*   idxb          = (int*)(ws + 131072);                   // 128 KB
  float* scsb          = (float*)(ws + 262144);                 // 128 KB
  int*   slotOfb       = (int*)(ws + 393216);                   // 128 KB
  int*   cntb          = (int*)(ws + 524288);                   // 4 KB
  unsigned short* xb   = (unsigned short*)(ws + 536576);        // 8 MB
  const size_t HEAD    = 536576;

  hipMemsetAsync(ws + 131072, 0, 262144, stream);       // idxb + scsb = 0
  hipMemsetAsync(ws + 393216, 0xFF, 131072, stream);    // slotOf = -1
  hipMemsetAsync(ws + 524288, 0, 4096, stream);         // cntb = 0
  probe_kernel<<<T_DIM / 4, 256, 0, stream>>>(x, Wp, bp, tb, gm, wdp, scale);
  compact_kernel<<<E_NUM, 256, 0, stream>>>(scale, idxb, scsb, cntb, slotOfb);
  cvt_kernel<<<T_DIM * D_DIM / 1024, 256, 0, stream>>>(x, xb);

  const size_t FULL_REQ = HEAD + 8388608 + 3 * (WSZ * 2) * E_NUM + HSZ * 2 * E_NUM; // ~243.8 MB
  if (ws_size >= FULL_REQ) {
    // -------- fused path
    unsigned short* wub = xb + (size_t)T_DIM * D_DIM;           // 32 MB
    unsigned short* wgb = wub + WSZ * E_NUM;                    // 32 MB
    unsigned short* wdb = wgb + WSZ * E_NUM;                    // 32 MB
    unsigned short* hb  = wdb + WSZ * E_NUM;                    // 128 MB

    dim3 gc(WSZ * E_NUM / 1024, 3);
    cvt_w_kernel<<<gc, 256, 0, stream>>>(Wu, Wg, Wd, wub, wgb, wdb);

    // expert-affine XCD-swizzled 1D grids
    upgate_kernel<<<dim3(4096, 1, 1), 256, 0, stream>>>(xb, wub, wgb, WSZ, HSZ,
                                                        idxb, scsb, cntb, 0, hb);
    // de (bf16, [E][T][D] = 64 MB) reuses the wub+wgb region — dead after upgate
    unsigned short* de = wub;
    down_slots_kernel<<<dim3(2048, 1, 1), 256, 0, stream>>>(hb, wdb, cntb, de);
    combine_kernel<<<dim3(T_DIM, 1, 1), 256, 0, stream>>>(de, slotOfb, out);
  } else {
    // -------- fallback (~37 MB): per-expert loop, atomic down, out pre-zeroed
    hipMemsetAsync(out, 0, (size_t)T_DIM * D_DIM * sizeof(float), stream);
    unsigned short* wub = xb + (size_t)T_DIM * D_DIM;           // 4 MB
    unsigned short* wgb = wub + WSZ;                            // 4 MB
    unsigned short* wdb = wgb + WSZ;                            // 4 MB
    unsigned short* hb  = wdb + WSZ;                            // 16 MB

    for (int e = 0; e < E_NUM; e++) {
      cvt3_kernel<<<3 * (DFF * D_DIM / 1024), 256, 0, stream>>>(
          Wu + e * WSZ, Wg + e * WSZ, Wd + e * WSZ, wub, wgb, wdb);
      dim3 g1(T_DIM / 128, DFF / 128, 1);
      upgate_kernel<<<g1, 256, 0, stream>>>(xb, wub, wgb, 0, 0, idxb, scsb, cntb, e, hb);
      dim3 g2(T_DIM / 128, D_DIM / 128, 1);
      down_kernel<<<g2, 256, 0, stream>>>(hb, wdb, 0, 0, idxb, cntb, e, out);
    }
  }
}

// Round 11
// 460.464 us; speedup vs baseline: 1.2251x; 1.0243x over previous
//
#include <hip/hip_runtime.h>
#include <hip/hip_bf16.h>

#define T_DIM 4096
#define D_DIM 1024
#define DFF   2048
#define E_NUM 8

typedef short short8 __attribute__((ext_vector_type(8)));
typedef float f32x4  __attribute__((ext_vector_type(4)));

__device__ __forceinline__ unsigned short f2bf(float f) {
  union { float f; unsigned u; } v; v.f = f;
  unsigned r = v.u + 0x7FFFu + ((v.u >> 16) & 1u);   // round-to-nearest-even
  return (unsigned short)(r >> 16);
}

__device__ __forceinline__ float bf2f(unsigned short b) {
  union { unsigned u; float f; } v; v.u = ((unsigned)b) << 16; return v.f;
}

__device__ __forceinline__ void load_lds16(const unsigned short* g, unsigned short* l) {
  __builtin_amdgcn_global_load_lds((const __attribute__((address_space(1))) void*)g,
                                   (__attribute__((address_space(3))) void*)l, 16, 0, 0);
}

// ---------------- probe: one wave per token, all 8 experts (x read once).
__global__ void probe_kernel(const float* __restrict__ x, const float* __restrict__ Wp,
                             const float* __restrict__ bp, const float* __restrict__ tb,
                             const float* __restrict__ gm, const float* __restrict__ wdp,
                             float* __restrict__ scale) {
  int wave = threadIdx.x >> 6;
  int lane = threadIdx.x & 63;
  int t = blockIdx.x * 4 + wave;
  const float4* xr = (const float4*)(x + (size_t)t * D_DIM);
  float4 a[4];
#pragma unroll
  for (int k = 0; k < 4; k++) a[k] = xr[k * 64 + lane];
  float z = wdp[0] * 0.5f;                                  // w_depth * depth_ratio
  float tau = tb[0] + gm[0] * (z / (1.f + expf(-z)));       // tau_base + gamma*silu(z)
#pragma unroll
  for (int e = 0; e < E_NUM; e++) {
    const float4* wr = (const float4*)(Wp + (size_t)e * D_DIM);
    float acc = 0.f;
#pragma unroll
    for (int k = 0; k < 4; k++) {
      float4 b = wr[k * 64 + lane];
      acc += a[k].x * b.x + a[k].y * b.y + a[k].z * b.z + a[k].w * b.w;
    }
#pragma unroll
    for (int off = 32; off > 0; off >>= 1) acc += __shfl_down(acc, off);
    if (lane == 0) {
      float logit = acc + bp[e];
      scale[t * E_NUM + e] = (logit > tau) ? (1.f / (1.f + expf(-logit))) : 0.f;
    }
  }
}

// ---------------- per-expert token compaction + inverse map.
__global__ void compact_kernel(const float* __restrict__ scale, int* __restrict__ idxb,
                               float* __restrict__ scsb, int* __restrict__ cntb,
                               int* __restrict__ slotOfb) {
  int e = blockIdx.x;
  for (int t = threadIdx.x; t < T_DIM; t += 256) {
    float s = scale[t * E_NUM + e];
    if (s > 0.f) {                       // sigmoid(finite) > 0; inactive is exact 0
      int slot = atomicAdd(&cntb[e], 1);
      idxb[e * T_DIM + slot] = t;
      scsb[e * T_DIM + slot] = s;
      slotOfb[e * T_DIM + t] = slot;
    }
  }
}

// ---------------- fp32 -> bf16 converters
__global__ void cvt_kernel(const float* __restrict__ src, unsigned short* __restrict__ dst) {
  int i = blockIdx.x * 256 + threadIdx.x;   // one float4 per thread
  float4 v = ((const float4*)src)[i];
  ushort4 o;
  o.x = f2bf(v.x); o.y = f2bf(v.y); o.z = f2bf(v.z); o.w = f2bf(v.w);
  ((ushort4*)dst)[i] = o;
}

__global__ void cvt_w_kernel(const float* __restrict__ wu, const float* __restrict__ wg,
                             const float* __restrict__ wdn,
                             unsigned short* __restrict__ ou, unsigned short* __restrict__ og,
                             unsigned short* __restrict__ od) {
  int m = blockIdx.y;
  size_t i = (size_t)blockIdx.x * 256 + threadIdx.x;
  const float* s = (m == 0) ? wu : (m == 1) ? wg : wdn;
  unsigned short* d = (m == 0) ? ou : (m == 1) ? og : od;
  float4 v = ((const float4*)s)[i];
  ushort4 o;
  o.x = f2bf(v.x); o.y = f2bf(v.y); o.z = f2bf(v.z); o.w = f2bf(v.w);
  ((ushort4*)d)[i] = o;
}

__global__ void cvt3_kernel(const float* __restrict__ wu, const float* __restrict__ wg,
                            const float* __restrict__ wdn,
                            unsigned short* __restrict__ ou, unsigned short* __restrict__ og,
                            unsigned short* __restrict__ od) {
  int b = blockIdx.x;                 // 3 * 2048 blocks; 2048 per matrix
  int m = b >> 11;
  int i = (b & 2047) * 256 + threadIdx.x;
  const float* s = (m == 0) ? wu : (m == 1) ? wg : wdn;
  unsigned short* d = (m == 0) ? ou : (m == 1) ? og : od;
  float4 v = ((const float4*)s)[i];
  ushort4 o;
  o.x = f2bf(v.x); o.y = f2bf(v.y); o.z = f2bf(v.z); o.w = f2bf(v.w);
  ((ushort4*)d)[i] = o;
}

// ---------------- FUSED-PATH up+gate: 512 threads, BM=256 x BN=128 x BK=32.
// R10-verified single-barrier skeleton (4 buffers, lookahead-2, counted vmcnt):
// per body: issue stage ks+2 -> vmcnt(8) -> lgkm(0) -> barrier -> reads+MFMA.
// Buffer of stage ks re-targeted at body ks+2; its reads were drained by the
// lgkm(0) before body ks+1's barrier, which all waves pass first. 8 waves (2Mx4N),
// per-wave 128x32 output per tensor: 12 ds_reads : 32 MFMAs per stage.
__global__ void __launch_bounds__(512, 1)
upgate_big_kernel(const unsigned short* __restrict__ A,
                  const unsigned short* __restrict__ Bu_base,
                  const unsigned short* __restrict__ Bg_base,
                  size_t wstride, size_t hstride,
                  const int* __restrict__ idxb, const float* __restrict__ scsb,
                  const int* __restrict__ cntb,
                  unsigned short* __restrict__ H_base) {
  int wid = blockIdx.x;                  // 2048 = 8 expert * 16 x * 16 y
  const int e = wid & 7;                 // expert = XCD (round-robin affine)
  int i = wid >> 3;                      // 0..255
  const int x = i & 15;                  // slot tile (256 rows), fastest
  const int y = i >> 4;                  // 0..15 dff tile (128 cols)
  const int rowA0 = x * 256;
  if (rowA0 >= cntb[e]) return;          // uniform early-exit
  __shared__ unsigned short smem[4 * 16384];   // 131072 B: 4 buf x (A 16K + Bu 8K + Bg 8K)
  const unsigned short* Bu = Bu_base + (size_t)e * wstride;
  const unsigned short* Bg = Bg_base + (size_t)e * wstride;
  unsigned short* H = H_base + (size_t)e * hstride;
  const int tid = threadIdx.x;
  const int wave = tid >> 6, lane = tid & 63;
  const int quad = lane >> 4, l15 = lane & 15;
  const int wm = (wave >> 2) * 128;      // 2 M halves of 128 rows
  const int wn = (wave & 3) * 32;        // 4 N quarters of 32 cols
  const int rowB0 = y * 128;

  f32x4 accU[8][2], accG[8][2];
#pragma unroll
  for (int m = 0; m < 8; m++)
#pragma unroll
    for (int n = 0; n < 2; n++) {
      accU[m][n] = (f32x4){0.f, 0.f, 0.f, 0.f};
      accG[m][n] = (f32x4){0.f, 0.f, 0.f, 0.f};
    }

  const int j0 = tid, j1 = tid + 512;          // A: 1024 x 16B chunks (256 rows x 4)
  const int ar0 = rowA0 + (j0 >> 2), ar1 = rowA0 + (j1 >> 2);
  const int cA0 = (j0 & 3) * 8, cA1 = (j1 & 3) * 8;
  const int brB = rowB0 + (tid >> 2);          // B: 512 chunks (128 rows x 4)
  const int cB = (tid & 3) * 8;
  const int ta0 = idxb[e * T_DIM + ar0];       // slot -> token (pads -> 0, scs=0)
  const int ta1 = idxb[e * T_DIM + ar1];

#define UG_STAGE(buf, kk) do {                                                  \
    unsigned short* _b = smem + (buf) * 16384;                                  \
    load_lds16(A  + (size_t)ta0 * D_DIM + (kk) + cA0, _b + j0 * 8);             \
    load_lds16(A  + (size_t)ta1 * D_DIM + (kk) + cA1, _b + j1 * 8);             \
    load_lds16(Bu + (size_t)brB * D_DIM + (kk) + cB, _b + 8192 + tid * 8);      \
    load_lds16(Bg + (size_t)brB * D_DIM + (kk) + cB, _b + 12288 + tid * 8);     \
  } while (0)

  UG_STAGE(0, 0);                              // prologue: stages 0,1 in flight
  UG_STAGE(1, 32);
  for (int ks = 0; ks < 32; ks++) {
    if (ks < 30) {
      UG_STAGE((ks + 2) & 3, (ks + 2) * 32);   // issue stage ks+2 (4 loads)
      asm volatile("s_waitcnt vmcnt(8)" ::: "memory");   // stage ks landed
    } else if (ks == 30) {
      asm volatile("s_waitcnt vmcnt(4)" ::: "memory");
    } else {
      asm volatile("s_waitcnt vmcnt(0)" ::: "memory");
    }
    // drain previous stage's ds_reads (retired during its MFMA phase), then the
    // single barrier: stage-ks data visible AND buf (ks-2) freed for overwrite.
    asm volatile("s_waitcnt lgkmcnt(0)" ::: "memory");
    __builtin_amdgcn_sched_barrier(0);
    __builtin_amdgcn_s_barrier();
    __builtin_amdgcn_sched_barrier(0);

    unsigned short* sA = smem + (ks & 3) * 16384;
    unsigned short* sU = sA + 8192;
    unsigned short* sG = sA + 12288;
    short8 af[8], bu[2], bg[2];
#pragma unroll
    for (int mt = 0; mt < 8; mt++)
      af[mt] = *(const short8*)(sA + (wm + mt * 16 + l15) * 32 + quad * 8);
#pragma unroll
    for (int nt = 0; nt < 2; nt++) {
      bu[nt] = *(const short8*)(sU + (wn + nt * 16 + l15) * 32 + quad * 8);
      bg[nt] = *(const short8*)(sG + (wn + nt * 16 + l15) * 32 + quad * 8);
    }
#pragma unroll
    for (int mt = 0; mt < 8; mt++)
#pragma unroll
      for (int nt = 0; nt < 2; nt++) {
        accU[mt][nt] = __builtin_amdgcn_mfma_f32_16x16x32_bf16(af[mt], bu[nt], accU[mt][nt], 0, 0, 0);
        accG[mt][nt] = __builtin_amdgcn_mfma_f32_16x16x32_bf16(af[mt], bg[nt], accG[mt][nt], 0, 0, 0);
      }
    __builtin_amdgcn_sched_barrier(0);         // keep reads/MFMA inside this body
  }
#undef UG_STAGE

  // epilogue: h' = scs[e,slot] * up * silu(gate)  (C/D: col=lane&15, row=quad*4+reg)
#pragma unroll
  for (int mt = 0; mt < 8; mt++) {
#pragma unroll
    for (int r = 0; r < 4; r++) {
      int row = rowA0 + wm + mt * 16 + quad * 4 + r;
      float s = scsb[e * T_DIM + row];
#pragma unroll
      for (int nt = 0; nt < 2; nt++) {
        int col = rowB0 + wn + nt * 16 + l15;
        float u = accU[mt][nt][r];
        float g = accG[mt][nt][r];
        float h = s * u * (g / (1.f + __expf(-g)));
        H[(size_t)row * DFF + col] = f2bf(h);
      }
    }
  }
}

// ---------------- FUSED-PATH down pass 1: 512 threads, BM=256 x BN=256 x BK=32.
// Same single-barrier skeleton; one-round grid (224 active blocks <= 256 CUs).
// A = contiguous h slot rows, B = wd; plain bf16 stores to de.
__global__ void __launch_bounds__(512, 1)
down_big_kernel(const unsigned short* __restrict__ hb,   // [E][slot][DFF]
                const unsigned short* __restrict__ wdb,  // [E][D][DFF]
                const int* __restrict__ cntb,
                unsigned short* __restrict__ de) {       // [E][T][D] bf16
  int wid = blockIdx.x;                  // 512 = 8 expert * 16 x * 4 y
  const int e = wid & 7;                 // expert = XCD
  int i = wid >> 3;                      // 0..63
  const int x = i & 15;                  // slot tile (256 rows), fastest
  const int y = i >> 4;                  // 0..3 D tile (256 cols)
  const int rowA0 = x * 256;
  if (rowA0 >= cntb[e]) return;          // uniform early-exit
  const size_t HSZ = (size_t)T_DIM * DFF;
  const size_t WSZ = (size_t)D_DIM * DFF;
  __shared__ unsigned short smem[4 * 16384];   // 131072 B: 4 buf x (A 16K + B 16K)
  const unsigned short* A = hb + (size_t)e * HSZ;
  const unsigned short* B = wdb + (size_t)e * WSZ;
  const int tid = threadIdx.x;
  const int wave = tid >> 6, lane = tid & 63;
  const int quad = lane >> 4, l15 = lane & 15;
  const int wm = (wave >> 2) * 128;      // 2 M halves of 128 rows
  const int wn = (wave & 3) * 64;        // 4 N quarters of 64 cols
  const int rowB0 = y * 256;

  f32x4 acc[8][4];
#pragma unroll
  for (int m = 0; m < 8; m++)
#pragma unroll
    for (int n = 0; n < 4; n++) acc[m][n] = (f32x4){0.f, 0.f, 0.f, 0.f};

  const int j0 = tid, j1 = tid + 512;          // 1024 chunks per 16KB tile
  const int ar0 = rowA0 + (j0 >> 2), ar1 = rowA0 + (j1 >> 2);
  const int br0 = rowB0 + (j0 >> 2), br1 = rowB0 + (j1 >> 2);
  const int c0 = (j0 & 3) * 8, c1 = (j1 & 3) * 8;

#define DS_STAGE(buf, kk) do {                                                  \
    unsigned short* _b = smem + (buf) * 16384;                                  \
    load_lds16(A + (size_t)ar0 * DFF + (kk) + c0, _b + j0 * 8);                 \
    load_lds16(A + (size_t)ar1 * DFF + (kk) + c1, _b + j1 * 8);                 \
    load_lds16(B + (size_t)br0 * DFF + (kk) + c0, _b + 8192 + j0 * 8);          \
    load_lds16(B + (size_t)br1 * DFF + (kk) + c1, _b + 8192 + j1 * 8);          \
  } while (0)

  DS_STAGE(0, 0);                              // prologue: stages 0,1 in flight
  DS_STAGE(1, 32);
  for (int ks = 0; ks < 64; ks++) {
    if (ks < 62) {
      DS_STAGE((ks + 2) & 3, (ks + 2) * 32);   // issue stage ks+2 (4 loads)
      asm volatile("s_waitcnt vmcnt(8)" ::: "memory");   // stage ks landed
    } else if (ks == 62) {
      asm volatile("s_waitcnt vmcnt(4)" ::: "memory");
    } else {
      asm volatile("s_waitcnt vmcnt(0)" ::: "memory");
    }
    asm volatile("s_waitcnt lgkmcnt(0)" ::: "memory");
    __builtin_amdgcn_sched_barrier(0);
    __builtin_amdgcn_s_barrier();
    __builtin_amdgcn_sched_barrier(0);

    unsigned short* sA = smem + (ks & 3) * 16384;
    unsigned short* sB = sA + 8192;
    short8 af[8], bf[4];
#pragma unroll
    for (int mt = 0; mt < 8; mt++)
      af[mt] = *(const short8*)(sA + (wm + mt * 16 + l15) * 32 + quad * 8);
#pragma unroll
    for (int nt = 0; nt < 4; nt++)
      bf[nt] = *(const short8*)(sB + (wn + nt * 16 + l15) * 32 + quad * 8);
#pragma unroll
    for (int mt = 0; mt < 8; mt++)
#pragma unroll
      for (int nt = 0; nt < 4; nt++)
        acc[mt][nt] = __builtin_amdgcn_mfma_f32_16x16x32_bf16(af[mt], bf[nt], acc[mt][nt], 0, 0, 0);
    __builtin_amdgcn_sched_barrier(0);
  }
#undef DS_STAGE

  // plain store to compacted per-expert output (bf16)
#pragma unroll
  for (int mt = 0; mt < 8; mt++) {
#pragma unroll
    for (int r = 0; r < 4; r++) {
      int row = rowA0 + wm + mt * 16 + quad * 4 + r;    // slot
#pragma unroll
      for (int nt = 0; nt < 4; nt++) {
        int col = rowB0 + wn + nt * 16 + l15;
        de[((size_t)e * T_DIM + row) * D_DIM + col] = f2bf(acc[mt][nt][r]);
      }
    }
  }
}

// ---------------- down pass 2: gather-combine. out[t,:] = sum_e de[e][slotOf[e][t],:].
__global__ void combine_kernel(const unsigned short* __restrict__ de,
                               const int* __restrict__ slotOfb,
                               float* __restrict__ out) {
  int t = blockIdx.x;                    // 4096
  int d4 = threadIdx.x;                  // 256 chunks of 4 elems
  float4 acc = {0.f, 0.f, 0.f, 0.f};
#pragma unroll
  for (int e = 0; e < E_NUM; e++) {
    int s = slotOfb[e * T_DIM + t];      // block-uniform
    if (s >= 0) {
      ushort4 v = ((const ushort4*)(de + ((size_t)e * T_DIM + s) * D_DIM))[d4];
      acc.x += bf2f(v.x); acc.y += bf2f(v.y); acc.z += bf2f(v.z); acc.w += bf2f(v.w);
    }
  }
  ((float4*)(out + (size_t)t * D_DIM))[d4] = acc;
}

// ---------------- fallback up+gate (R7-verified 256-thread version, 3D grid)
__global__ void __launch_bounds__(256, 2)
upgate_kernel(const unsigned short* __restrict__ A,
              const unsigned short* __restrict__ Bu_base,
              const unsigned short* __restrict__ Bg_base,
              size_t wstride, size_t hstride,
              const int* __restrict__ idxb, const float* __restrict__ scsb,
              const int* __restrict__ cntb, int e_base,
              unsigned short* __restrict__ H_base) {
  int x = blockIdx.x, y = blockIdx.y, z = blockIdx.z;
  const int e = e_base + z;
  const int rowA0 = x * 128;
  if (rowA0 >= cntb[e]) return;
  __shared__ unsigned short smem[3 * 12288];
  const unsigned short* Bu = Bu_base + (size_t)z * wstride;
  const unsigned short* Bg = Bg_base + (size_t)z * wstride;
  unsigned short* H = H_base + (size_t)z * hstride;
  const int tid = threadIdx.x;
  const int wave = tid >> 6, lane = tid & 63;
  const int quad = lane >> 4, l15 = lane & 15;
  const int wm = (wave >> 1) * 64, wn = (wave & 1) * 64;
  const int rowB0 = y * 128;

  f32x4 accU[4][4], accG[4][4];
#pragma unroll
  for (int i2 = 0; i2 < 4; i2++)
#pragma unroll
    for (int j = 0; j < 4; j++) {
      accU[i2][j] = (f32x4){0.f, 0.f, 0.f, 0.f};
      accG[i2][j] = (f32x4){0.f, 0.f, 0.f, 0.f};
    }

  const int j0 = tid, j1 = tid + 256;
  const int ar0 = rowA0 + (j0 >> 2), ar1 = rowA0 + (j1 >> 2);
  const int br0 = rowB0 + (j0 >> 2), br1 = rowB0 + (j1 >> 2);
  const int c0 = (j0 & 3) * 8, c1 = (j1 & 3) * 8;
  const int ta0 = idxb[e * T_DIM + ar0];
  const int ta1 = idxb[e * T_DIM + ar1];

#define UGF_STAGE(buf, kk) do {                                                \
    unsigned short* _b = smem + (buf) * 12288;                                 \
    load_lds16(A  + (size_t)ta0 * D_DIM + (kk) + c0, _b + j0 * 8);             \
    load_lds16(A  + (size_t)ta1 * D_DIM + (kk) + c1, _b + j1 * 8);             \
    load_lds16(Bu + (size_t)br0 * D_DIM + (kk) + c0, _b + 4096 + j0 * 8);      \
    load_lds16(Bu + (size_t)br1 * D_DIM + (kk) + c1, _b + 4096 + j1 * 8);      \
    load_lds16(Bg + (size_t)br0 * D_DIM + (kk) + c0, _b + 8192 + j0 * 8);      \
    load_lds16(Bg + (size_t)br1 * D_DIM + (kk) + c1, _b + 8192 + j1 * 8);      \
  } while (0)

  UGF_STAGE(0, 0);
  UGF_STAGE(1, 32);
  for (int ks = 0; ks < 32; ks++) {
    if (ks < 30) {
      UGF_STAGE((ks + 2) % 3, (ks + 2) * 32);
      asm volatile("s_waitcnt vmcnt(12)" ::: "memory");
    } else if (ks == 30) {
      asm volatile("s_waitcnt vmcnt(6)" ::: "memory");
    } else {
      asm volatile("s_waitcnt vmcnt(0)" ::: "memory");
    }
    __builtin_amdgcn_sched_barrier(0);
    __builtin_amdgcn_s_barrier();
    __builtin_amdgcn_sched_barrier(0);

    unsigned short* sA = smem + (ks % 3) * 12288;
    unsigned short* sU = sA + 4096;
    unsigned short* sG = sA + 8192;
    short8 af[4], bu[4], bg[4];
#pragma unroll
    for (int mt = 0; mt < 4; mt++)
      af[mt] = *(const short8*)(sA + (wm + mt * 16 + l15) * 32 + quad * 8);
#pragma unroll
    for (int nt = 0; nt < 4; nt++) {
      bu[nt] = *(const short8*)(sU + (wn + nt * 16 + l15) * 32 + quad * 8);
      bg[nt] = *(const short8*)(sG + (wn + nt * 16 + l15) * 32 + quad * 8);
    }
#pragma unroll
    for (int mt = 0; mt < 4; mt++)
#pragma unroll
      for (int nt = 0; nt < 4; nt++) {
        accU[mt][nt] = __builtin_amdgcn_mfma_f32_16x16x32_bf16(af[mt], bu[nt], accU[mt][nt], 0, 0, 0);
        accG[mt][nt] = __builtin_amdgcn_mfma_f32_16x16x32_bf16(af[mt], bg[nt], accG[mt][nt], 0, 0, 0);
      }
    asm volatile("s_waitcnt lgkmcnt(0)" ::: "memory");
    __builtin_amdgcn_sched_barrier(0);
    __builtin_amdgcn_s_barrier();
    __builtin_amdgcn_sched_barrier(0);
  }
#undef UGF_STAGE

#pragma unroll
  for (int mt = 0; mt < 4; mt++) {
#pragma unroll
    for (int r = 0; r < 4; r++) {
      int row = rowA0 + wm + mt * 16 + quad * 4 + r;
      float s = scsb[e * T_DIM + row];
#pragma unroll
      for (int nt = 0; nt < 4; nt++) {
        int col = rowB0 + wn + nt * 16 + l15;
        float u = accU[mt][nt][r];
        float g = accG[mt][nt][r];
        float h = s * u * (g / (1.f + __expf(-g)));
        H[(size_t)row * DFF + col] = f2bf(h);
      }
    }
  }
}

// ---------------- fallback down (atomic scatter) — used only when ws small
__global__ void __launch_bounds__(256, 2)
down_kernel(const unsigned short* __restrict__ A_base,
            const unsigned short* __restrict__ B_base,
            size_t hstride, size_t wstride,
            const int* __restrict__ idxb, const int* __restrict__ cntb, int e_base,
            float* __restrict__ out) {
  const int e = e_base + blockIdx.z;
  const int rowA0 = blockIdx.x * 128;
  if (rowA0 >= cntb[e]) return;
  __shared__ unsigned short smem[2 * 128 * 32];
  unsigned short* sA = smem;
  unsigned short* sB = smem + 4096;
  const unsigned short* A = A_base + (size_t)blockIdx.z * hstride;
  const unsigned short* B = B_base + (size_t)blockIdx.z * wstride;
  const int tid = threadIdx.x;
  const int wave = tid >> 6, lane = tid & 63;
  const int quad = lane >> 4, l15 = lane & 15;
  const int wm = (wave >> 1) * 64, wn = (wave & 1) * 64;
  const int rowB0 = blockIdx.y * 128;

  f32x4 acc[4][4];
#pragma unroll
  for (int i = 0; i < 4; i++)
#pragma unroll
    for (int j = 0; j < 4; j++) acc[i][j] = (f32x4){0.f, 0.f, 0.f, 0.f};

  const int j0 = tid, j1 = tid + 256;
  const int ar0 = rowA0 + (j0 >> 2), ar1 = rowA0 + (j1 >> 2);
  const int br0 = rowB0 + (j0 >> 2), br1 = rowB0 + (j1 >> 2);
  const int c0 = (j0 & 3) * 8, c1 = (j1 & 3) * 8;

  for (int k0 = 0; k0 < DFF; k0 += 32) {
    __syncthreads();
    load_lds16(A + (size_t)ar0 * DFF + k0 + c0, sA + j0 * 8);
    load_lds16(A + (size_t)ar1 * DFF + k0 + c1, sA + j1 * 8);
    load_lds16(B + (size_t)br0 * DFF + k0 + c0, sB + j0 * 8);
    load_lds16(B + (size_t)br1 * DFF + k0 + c1, sB + j1 * 8);
    __syncthreads();

    short8 af[4], bf[4];
#pragma unroll
    for (int mt = 0; mt < 4; mt++)
      af[mt] = *(const short8*)(sA + (wm + mt * 16 + l15) * 32 + quad * 8);
#pragma unroll
    for (int nt = 0; nt < 4; nt++)
      bf[nt] = *(const short8*)(sB + (wn + nt * 16 + l15) * 32 + quad * 8);
#pragma unroll
    for (int mt = 0; mt < 4; mt++)
#pragma unroll
      for (int nt = 0; nt < 4; nt++)
        acc[mt][nt] = __builtin_amdgcn_mfma_f32_16x16x32_bf16(af[mt], bf[nt], acc[mt][nt], 0, 0, 0);
  }

#pragma unroll
  for (int mt = 0; mt < 4; mt++) {
#pragma unroll
    for (int r = 0; r < 4; r++) {
      int row = rowA0 + wm + mt * 16 + quad * 4 + r;
      int tok = idxb[e * T_DIM + row];
#pragma unroll
      for (int nt = 0; nt < 4; nt++) {
        int col = rowB0 + wn + nt * 16 + l15;
        atomicAdd(&out[(size_t)tok * D_DIM + col], acc[mt][nt][r]);
      }
    }
  }
}

extern "C" void kernel_launch(void* const* d_in, const int* in_sizes, int n_in,
                              void* d_out, int out_size, void* d_ws, size_t ws_size,
                              hipStream_t stream) {
  const float* x   = (const float*)d_in[0];
  const float* Wp  = (const float*)d_in[1];
  const float* bp  = (const float*)d_in[2];
  const float* Wu  = (const float*)d_in[3];
  const float* Wg  = (const float*)d_in[4];
  const float* Wd  = (const float*)d_in[5];
  const float* tb  = (const float*)d_in[6];
  const float* gm  = (const float*)d_in[7];
  const float* wdp = (const float*)d_in[8];
  float* out = (float*)d_out;

  const size_t WSZ = (size_t)DFF * D_DIM;          // elements per expert weight matrix
  const size_t HSZ = (size_t)T_DIM * DFF;          // elements per expert h

  char* ws = (char*)d_ws;
  float* scale         = (float*)ws;                            // 128 KB @ 0
  int*   idxb          = (int*)(ws + 131072);                   // 128 KB
  float* scsb          = (float*)(ws + 262144);                 // 128 KB
  int*   slotOfb       = (int*)(ws + 393216);                   // 128 KB
  int*   cntb          = (int*)(ws + 524288);                   // 4 KB
  unsigned short* xb   = (unsigned short*)(ws + 536576);        // 8 MB
  const size_t HEAD    = 536576;

  hipMemsetAsync(ws + 131072, 0, 262144, stream);       // idxb + scsb = 0
  hipMemsetAsync(ws + 393216, 0xFF, 131072, stream);    // slotOf = -1
  hipMemsetAsync(ws + 524288, 0, 4096, stream);         // cntb = 0
  probe_kernel<<<T_DIM / 4, 256, 0, stream>>>(x, Wp, bp, tb, gm, wdp, scale);
  compact_kernel<<<E_NUM, 256, 0, stream>>>(scale, idxb, scsb, cntb, slotOfb);
  cvt_kernel<<<T_DIM * D_DIM / 1024, 256, 0, stream>>>(x, xb);

  const size_t FULL_REQ = HEAD + 8388608 + 3 * (WSZ * 2) * E_NUM + HSZ * 2 * E_NUM; // ~243.8 MB
  if (ws_size >= FULL_REQ) {
    // -------- fused path
    unsigned short* wub = xb + (size_t)T_DIM * D_DIM;           // 32 MB
    unsigned short* wgb = wub + WSZ * E_NUM;                    // 32 MB
    unsigned short* wdb = wgb + WSZ * E_NUM;                    // 32 MB
    unsigned short* hb  = wdb + WSZ * E_NUM;                    // 128 MB

    dim3 gc(WSZ * E_NUM / 1024, 3);
    cvt_w_kernel<<<gc, 256, 0, stream>>>(Wu, Wg, Wd, wub, wgb, wdb);

    // expert-affine XCD-swizzled big-tile GEMMs (512 threads, 1 block/CU)
    upgate_big_kernel<<<dim3(2048, 1, 1), 512, 0, stream>>>(xb, wub, wgb, WSZ, HSZ,
                                                            idxb, scsb, cntb, hb);
    // de (bf16, [E][T][D] = 64 MB) reuses the wub+wgb region — dead after upgate
    unsigned short* de = wub;
    down_big_kernel<<<dim3(512, 1, 1), 512, 0, stream>>>(hb, wdb, cntb, de);
    combine_kernel<<<dim3(T_DIM, 1, 1), 256, 0, stream>>>(de, slotOfb, out);
  } else {
    // -------- fallback (~37 MB): per-expert loop, atomic down, out pre-zeroed
    hipMemsetAsync(out, 0, (size_t)T_DIM * D_DIM * sizeof(float), stream);
    unsigned short* wub = xb + (size_t)T_DIM * D_DIM;           // 4 MB
    unsigned short* wgb = wub + WSZ;                            // 4 MB
    unsigned short* wdb = wgb + WSZ;                            // 4 MB
    unsigned short* hb  = wdb + WSZ;                            // 16 MB

    for (int e = 0; e < E_NUM; e++) {
      cvt3_kernel<<<3 * (DFF * D_DIM / 1024), 256, 0, stream>>>(
          Wu + e * WSZ, Wg + e * WSZ, Wd + e * WSZ, wub, wgb, wdb);
      dim3 g1(T_DIM / 128, DFF / 128, 1);
      upgate_kernel<<<g1, 256, 0, stream>>>(xb, wub, wgb, 0, 0, idxb, scsb, cntb, e, hb);
      dim3 g2(T_DIM / 128, D_DIM / 128, 1);
      down_kernel<<<g2, 256, 0, stream>>>(hb, wdb, 0, 0, idxb, cntb, e, out);
    }
  }
}